// Round 17
// baseline (243.113 us; speedup 1.0000x reference)
//
#include <hip/hip_runtime.h>
#include <math.h>

// Problem constants
#define NB 64    // N batch
#define LL 128   // L
#define DV 16
#define DD 256   // D
#define HH 8     // heads
#define DK 32    // D/H
#define FF 1024
#define LC 3
#define KNN 6
#define MS 16
#define WLS 786432   // per-layer transposed-weight stride (elems)

typedef __attribute__((ext_vector_type(8))) short s16x8;   // 8 bf16 (4 VGPR)
typedef __attribute__((ext_vector_type(4))) float f32x4;   // MFMA acc

static __device__ inline unsigned short f2b(float x) {
    union { float f; unsigned int u; } v; v.f = x;
    unsigned int r = (v.u + 0x7FFFu + ((v.u >> 16) & 1u)) >> 16;
    return (unsigned short)r;
}

// global -> LDS direct (16B per lane; dest = wave-uniform base + lane*16)
static __device__ __forceinline__ void glds16(const void* g, void* l) {
    __builtin_amdgcn_global_load_lds(
        (const __attribute__((address_space(1))) void*)g,
        (__attribute__((address_space(3))) void*)l, 16, 0, 0);
}

// ---------------------------------------------------------------------------
// Uber preprocessing: [0,2048) proj | [2048,4096) knn | [4096,6400) transpose
// ---------------------------------------------------------------------------
__global__ __launch_bounds__(256)
void uber_pre(const float* __restrict__ veh, const float* __restrict__ Wp,
              const float* __restrict__ bp, float* __restrict__ h,
              unsigned short* __restrict__ hb,
              const float* __restrict__ edges, unsigned long long* __restrict__ idx8,
              const float* __restrict__ Wq, const float* __restrict__ Wk,
              const float* __restrict__ Wv, const float* __restrict__ Wo,
              const float* __restrict__ f1, const float* __restrict__ f2,
              unsigned short* __restrict__ Wt) {
    int bx = blockIdx.x;
    if (bx < 2048) {
        int m = bx * 4 + (threadIdx.x >> 6);
        int l = threadIdx.x & 63;
        int c0 = l * 4;
        const float4* w4 = reinterpret_cast<const float4*>(Wp);
        float4 a = *reinterpret_cast<const float4*>(bp + c0);
        const float* vr = veh + (size_t)m * DV;
#pragma unroll
        for (int t = 0; t < DV; ++t) {
            float vt = vr[t];
            float4 wv = w4[t * 64 + l];
            a.x += vt * wv.x; a.y += vt * wv.y; a.z += vt * wv.z; a.w += vt * wv.w;
        }
        *reinterpret_cast<float4*>(h + (size_t)m * DD + c0) = a;
        ushort4 u; u.x = f2b(a.x); u.y = f2b(a.y); u.z = f2b(a.z); u.w = f2b(a.w);
        *reinterpret_cast<ushort4*>(hb + (size_t)m * DD + c0) = u;
        return;
    }
    if (bx < 4096) {
        int row = (bx - 2048) * 4 + (threadIdx.x >> 6);
        int lane = threadIdx.x & 63;
        const float* dr = edges + (size_t)row * LL * 4;
        float v0 = dr[lane * 4], v1 = dr[(lane + 64) * 4];
        int i0 = lane, i1 = lane + 64;
        unsigned long long packed = 0;
#pragma unroll
        for (int k = 0; k < KNN; ++k) {
            float v; int i;
            if (v1 < v0) { v = v1; i = i1; } else { v = v0; i = i0; }
#pragma unroll
            for (int o = 1; o < 64; o <<= 1) {
                float ov = __shfl_xor(v, o);
                int oi = __shfl_xor(i, o);
                if (ov < v || (ov == v && oi < i)) { v = ov; i = oi; }
            }
            packed |= (unsigned long long)i << (k * 8);
            if (i == i0) v0 = 3.4e38f;
            if (i == i1) v1 = 3.4e38f;
        }
        if (lane == 0) idx8[row] = packed;
        return;
    }
    {
        int t = bx - 4096;            // < 2304
        int ll = t / 768, r = t % 768;
        int w, tile, K, N;
        if (r < 256)      { w = r >> 6; tile = r & 63;  K = DD; N = DD; }
        else if (r < 512) { w = 4; tile = r - 256;      K = DD; N = FF; }
        else              { w = 5; tile = r - 512;      K = FF; N = DD; }
        const float* src = (w == 0) ? Wq : (w == 1) ? Wk : (w == 2) ? Wv :
                           (w == 3) ? Wo : (w == 4) ? f1 : f2;
        src += (size_t)ll * K * N;
        long off = (w == 4) ? 262144L : (w == 5) ? 524288L : (long)w * 65536L;
        unsigned short* dst = Wt + (size_t)ll * WLS + off;
        int ntx = N >> 5;
        int n0 = (tile % ntx) * 32, k0 = (tile / ntx) * 32;
        int tx = threadIdx.x & 31, ty = threadIdx.x >> 5;
        __shared__ float T[32][33];
#pragma unroll
        for (int rr = 0; rr < 4; ++rr)
            T[ty + rr * 8][tx] = src[(size_t)(k0 + ty + rr * 8) * N + n0 + tx];
        __syncthreads();
#pragma unroll
        for (int rr = 0; rr < 4; ++rr)
            dst[(size_t)(n0 + ty + rr * 8) * K + k0 + tx] = f2b(T[tx][ty + rr * 8]);
    }
}

// ---------------------------------------------------------------------------
// Unified MFMA GEMM, double-buffered: issue next K-step's global_load_lds
// BEFORE computing current step; ONE barrier per step.
// MODE 2: QKV scatter -> f32 head-major Oq/Ok/Ov (no bias).
// ---------------------------------------------------------------------------
template <int BM, int BN, int WR, int WC, int MODE>
__global__ __launch_bounds__(256)
void gg(const unsigned short* __restrict__ A, const unsigned short* __restrict__ Bt,
        const float* __restrict__ bias, unsigned short* __restrict__ Cb,
        float* __restrict__ Oq, float* __restrict__ Ok, float* __restrict__ Ov,
        int K, int N) {
    constexpr int MI = BM / (WR * 16);
    constexpr int NJ = BN / (WC * 16);
    __shared__ unsigned short As[2][BM * 32];
    __shared__ unsigned short Bs[2][BN * 32];
    int tid = threadIdx.x;
    int w = tid >> 6, l = tid & 63;
    int lr = l & 15, lg = l >> 4;
    int wr = w % WR, wc = w / WR;
    int m0 = blockIdx.y * BM, n0 = blockIdx.x * BN;
    int row = tid >> 2, seg = tid & 3;

    auto STAGE = [&](int buf, int k0) {
#pragma unroll
        for (int r = 0; r < BM / 64; ++r)
            glds16(A + (size_t)(m0 + r * 64 + row) * K + k0 + seg * 8,
                   As[buf] + r * 2048 + w * 512);
#pragma unroll
        for (int r = 0; r < BN / 64; ++r)
            glds16(Bt + (size_t)(n0 + r * 64 + row) * K + k0 + seg * 8,
                   Bs[buf] + r * 2048 + w * 512);
    };

    f32x4 acc[MI][NJ];
#pragma unroll
    for (int i = 0; i < MI; ++i)
#pragma unroll
        for (int j = 0; j < NJ; ++j) acc[i][j] = (f32x4)(0.f);

    STAGE(0, 0);
    int nsteps = K >> 5;
    for (int step = 0; step < nsteps; ++step) {
        int cur = step & 1;
        __syncthreads();   // drains buf[cur] loads; prior reads of buf[cur^1] done
        if (step + 1 < nsteps) STAGE(cur ^ 1, (step + 1) * 32);
        s16x8 af[MI], bf[NJ];
#pragma unroll
        for (int i = 0; i < MI; ++i)
            af[i] = *reinterpret_cast<const s16x8*>(
                As[cur] + (wr * MI * 16 + i * 16 + lr) * 32 + lg * 8);
#pragma unroll
        for (int j = 0; j < NJ; ++j)
            bf[j] = *reinterpret_cast<const s16x8*>(
                Bs[cur] + (wc * NJ * 16 + j * 16 + lr) * 32 + lg * 8);
#pragma unroll
        for (int i = 0; i < MI; ++i)
#pragma unroll
            for (int j = 0; j < NJ; ++j)
                acc[i][j] = __builtin_amdgcn_mfma_f32_16x16x32_bf16(af[i], bf[j], acc[i][j], 0, 0, 0);
    }

    if constexpr (MODE == 2) {
        int s = n0 >> 8;          // 0=q,1=k,2=v (64-wide tiles never cross 256)
        float* dst = (s == 0) ? Oq : (s == 1) ? Ok : Ov;
#pragma unroll
        for (int i = 0; i < MI; ++i)
#pragma unroll
            for (int j = 0; j < NJ; ++j) {
                int cc = (n0 & 255) + wc * NJ * 16 + j * 16 + lr;
                int hh = cc >> 5, dk = cc & 31;
                int grow = m0 + wr * MI * 16 + i * 16 + lg * 4;
                int nn = grow >> 7, rl = grow & 127;
                size_t ho = ((size_t)(nn * HH + hh) * LL + rl) * DK + dk;
#pragma unroll
                for (int q = 0; q < 4; ++q)
                    dst[ho + (size_t)q * DK] = acc[i][j][q];
            }
    } else {
#pragma unroll
        for (int i = 0; i < MI; ++i)
#pragma unroll
            for (int j = 0; j < NJ; ++j) {
                int col = n0 + wc * NJ * 16 + j * 16 + lr;
                float bc = bias[col];
#pragma unroll
                for (int q = 0; q < 4; ++q) {
                    int r = m0 + wr * MI * 16 + i * 16 + lg * 4 + q;
                    float v = fmaxf(acc[i][j][q] + bc, 0.f);
                    Cb[(size_t)r * N + col] = f2b(v);
                }
            }
    }
}

// ---------------------------------------------------------------------------
// Fused sparse-attention + Wo GEMM(16x256) + bias + residual + LayerNorm.
// 512 blocks, 4 waves; wave w owns cols w*64..+63. Double-buffered B staging.
// ---------------------------------------------------------------------------
__global__ __launch_bounds__(256)
void attnwo_ln(const unsigned short* __restrict__ Bt,
               const float* __restrict__ qh, const float* __restrict__ kh,
               const float* __restrict__ vh, const float* __restrict__ edges,
               const unsigned long long* __restrict__ idx8,
               const float* __restrict__ m1w, const float* __restrict__ m1b,
               const float* __restrict__ m2w, const float* __restrict__ m2b,
               const float* __restrict__ bias, const float* __restrict__ res,
               const float* __restrict__ g, const float* __restrict__ be,
               float* __restrict__ out, unsigned short* __restrict__ outb) {
    constexpr int KK = 256;
    __shared__ unsigned short Afull[16 * 264];   // attn-built A (bf16)
    __shared__ unsigned short Bs[2][256 * 32];   // 2 x 16 KB
    __shared__ float Red[16][4];
    int tid = threadIdx.x;
    int w = tid >> 6, l = tid & 63;
    int lr = l & 15, lg = l >> 4;
    int m0 = blockIdx.x * 16;

    {
        // ---- sparse kNN attention prologue: 128 tasks x 2 threads ----
        int task = tid >> 1, sub = tid & 1;
        int rl = task & 15, hh = task >> 4;
        int n = m0 >> 7, r = (m0 & 127) + rl;
        int bh = n * HH + hh;
        const float scale = 0.17677669529663687f;   // 1/sqrt(32)
        const float* w0g = m1w + (hh * 2 + 0) * MS;
        const float* w1g = m1w + (hh * 2 + 1) * MS;
        const float* b1g = m1b + hh * MS;
        const float* w2g = m2w + hh * MS;
        float b2v = m2b[hh];

        const float4* qr = reinterpret_cast<const float4*>(
            qh + ((size_t)bh * LL + r) * DK) + sub * 4;
        float4 q[4];
#pragma unroll
        for (int j = 0; j < 4; ++j) q[j] = qr[j];

        unsigned long long pk = idx8[(size_t)n * LL + r];
        const float* kbase = kh + (size_t)bh * LL * DK;
        const float* vbase = vh + (size_t)bh * LL * DK;
        const float* erow = edges + (size_t)(n * LL + r) * LL * 4;

        int col[KNN];
#pragma unroll
        for (int k = 0; k < KNN; ++k) col[k] = (int)((pk >> (k * 8)) & 0xFF);

        float e[KNN];
        float mx = -3.4e38f;
#pragma unroll
        for (int k = 0; k < KNN; ++k) {
            const float4* kr = reinterpret_cast<const float4*>(
                kbase + (size_t)col[k] * DK) + sub * 4;
            float d = 0.f;
#pragma unroll
            for (int j = 0; j < 4; ++j) {
                float4 kv = kr[j];
                d += q[j].x * kv.x + q[j].y * kv.y + q[j].z * kv.z + q[j].w * kv.w;
            }
            d += __shfl_xor(d, 1);      // merge the two 16-dim halves
            d *= scale;
            float cst = erow[col[k] * 4];
            float s = b2v;
#pragma unroll
            for (int m = 0; m < MS; ++m)
                s += fmaxf(d * w0g[m] + cst * w1g[m] + b1g[m], 0.f) * w2g[m];
            e[k] = s;
            mx = fmaxf(mx, s);
        }
        float sum = 0.f;
#pragma unroll
        for (int k = 0; k < KNN; ++k) { e[k] = __expf(e[k] - mx); sum += e[k]; }
        float inv = 1.f / sum;

        float4 att[4];
#pragma unroll
        for (int j = 0; j < 4; ++j) att[j] = make_float4(0.f, 0.f, 0.f, 0.f);
#pragma unroll
        for (int k = 0; k < KNN; ++k) {
            float wgt = e[k] * inv;
            const float4* vr = reinterpret_cast<const float4*>(
                vbase + (size_t)col[k] * DK) + sub * 4;
#pragma unroll
            for (int j = 0; j < 4; ++j) {
                float4 vv = vr[j];
                att[j].x += wgt * vv.x; att[j].y += wgt * vv.y;
                att[j].z += wgt * vv.z; att[j].w += wgt * vv.w;
            }
        }
        unsigned short* arow = Afull + rl * 264 + hh * DK + sub * 16;
#pragma unroll
        for (int j = 0; j < 4; ++j) {
            ushort4 u;
            u.x = f2b(att[j].x); u.y = f2b(att[j].y);
            u.z = f2b(att[j].z); u.w = f2b(att[j].w);
            *reinterpret_cast<ushort4*>(arow + j * 4) = u;
        }
    }

    auto STAGE = [&](int buf, int k0) {
#pragma unroll
        for (int i = 0; i < 4; ++i) {
            int idx = w * 4 + i;    // 16 wave-loads cover 256 B-rows
            glds16(Bt + (size_t)(idx * 16 + (l >> 2)) * KK + k0 + (l & 3) * 8,
                   Bs[buf] + idx * 512);
        }
    };

    f32x4 acc[4];
#pragma unroll
    for (int j = 0; j < 4; ++j) acc[j] = (f32x4)(0.f);

    STAGE(0, 0);
    constexpr int NSTEPS = KK >> 5;
    for (int step = 0; step < NSTEPS; ++step) {
        int cur = step & 1;
        __syncthreads();
        if (step + 1 < NSTEPS) STAGE(cur ^ 1, (step + 1) * 32);
        s16x8 af = *reinterpret_cast<const s16x8*>(Afull + lr * 264 + step * 32 + lg * 8);
#pragma unroll
        for (int j = 0; j < 4; ++j) {
            s16x8 bf = *reinterpret_cast<const s16x8*>(
                Bs[cur] + (w * 64 + j * 16 + lr) * 32 + lg * 8);
            acc[j] = __builtin_amdgcn_mfma_f32_16x16x32_bf16(af, bf, acc[j], 0, 0, 0);
        }
    }

    // ---- epilogue: bias + residual; cross-wave LN ----
    float rsum[4] = {0.f, 0.f, 0.f, 0.f};
#pragma unroll
    for (int j = 0; j < 4; ++j) {
        int col = w * 64 + j * 16 + lr;
        float bc = bias[col];
#pragma unroll
        for (int q = 0; q < 4; ++q) {
            float x = acc[j][q] + bc + res[(size_t)(m0 + lg * 4 + q) * DD + col];
            acc[j][q] = x;
            rsum[q] += x;
        }
    }
#pragma unroll
    for (int q = 0; q < 4; ++q)
#pragma unroll
        for (int o = 1; o < 16; o <<= 1) rsum[q] += __shfl_xor(rsum[q], o);
    __syncthreads();
    if (lr == 0)
#pragma unroll
        for (int q = 0; q < 4; ++q) Red[lg * 4 + q][w] = rsum[q];
    __syncthreads();
    float mean[4];
#pragma unroll
    for (int q = 0; q < 4; ++q) {
        int row = lg * 4 + q;
        mean[q] = (Red[row][0] + Red[row][1] + Red[row][2] + Red[row][3]) * (1.0f / 256.0f);
    }
    float ssum[4] = {0.f, 0.f, 0.f, 0.f};
#pragma unroll
    for (int j = 0; j < 4; ++j)
#pragma unroll
        for (int q = 0; q < 4; ++q) {
            float d = acc[j][q] - mean[q];
            ssum[q] += d * d;
        }
#pragma unroll
    for (int q = 0; q < 4; ++q)
#pragma unroll
        for (int o = 1; o < 16; o <<= 1) ssum[q] += __shfl_xor(ssum[q], o);
    __syncthreads();
    if (lr == 0)
#pragma unroll
        for (int q = 0; q < 4; ++q) Red[lg * 4 + q][w] = ssum[q];
    __syncthreads();
    float rstd[4];
#pragma unroll
    for (int q = 0; q < 4; ++q) {
        int row = lg * 4 + q;
        float var = (Red[row][0] + Red[row][1] + Red[row][2] + Red[row][3]) * (1.0f / 256.0f);
        rstd[q] = 1.0f / sqrtf(var + 1e-5f);
    }
#pragma unroll
    for (int j = 0; j < 4; ++j) {
        int col = w * 64 + j * 16 + lr;
        float gc = g[col], bc2 = be[col];
#pragma unroll
        for (int q = 0; q < 4; ++q) {
            size_t off = (size_t)(m0 + lg * 4 + q) * DD + col;
            float v = (acc[j][q] - mean[q]) * rstd[q] * gc + bc2;
            out[off] = v;
            outb[off] = f2b(v);
        }
    }
}

// ---------------------------------------------------------------------------
// Fused FF1(relu) + FF2 + bias + residual + LayerNorm. 512 blocks x 16 rows.
// Phase 1: A-frags preloaded in VGPRs (reused by all 4 N-chunks); W1^T via
//   dbuf glds; relu -> padded LDS fm[16][1032] (bf16).
// Phase 2: A-frags from fm; W2^T via same dbuf pipeline; LN epilogue.
// One continuous 64-stage pipeline; buffer parity lines up across phases.
// ---------------------------------------------------------------------------
__global__ __launch_bounds__(256)
void ff_ln(const unsigned short* __restrict__ hb_in,
           const unsigned short* __restrict__ W1t, const unsigned short* __restrict__ W2t,
           const float* __restrict__ b1, const float* __restrict__ b2,
           const float* __restrict__ res, const float* __restrict__ g,
           const float* __restrict__ be,
           float* __restrict__ out, unsigned short* __restrict__ outb) {
    __shared__ unsigned short fm[16 * 1032];     // 33 KB, stride 1032 (2-way free)
    __shared__ unsigned short Bs[2][256 * 32];   // 32 KB
    __shared__ float Red[16][4];
    int tid = threadIdx.x;
    int w = tid >> 6, l = tid & 63;
    int lr = l & 15, lg = l >> 4;
    int m0 = blockIdx.x * 16;

    // preload FF1 A-frags (K=256, 8 steps) into registers — reused per chunk
    s16x8 af1[8];
    {
        const unsigned short* arow = hb_in + (size_t)(m0 + lr) * DD + lg * 8;
#pragma unroll
        for (int s = 0; s < 8; ++s)
            af1[s] = *reinterpret_cast<const s16x8*>(arow + s * 32);
    }

    auto STAGE1 = [&](int buf, int stage) {      // stage<32: chunk=stage>>3
        int chunk = stage >> 3, k0 = (stage & 7) * 32;
        const unsigned short* base = W1t + (size_t)(chunk * 256) * DD;
#pragma unroll
        for (int i = 0; i < 4; ++i) {
            int idx = w * 4 + i;
            glds16(base + (size_t)(idx * 16 + (l >> 2)) * DD + k0 + (l & 3) * 8,
                   Bs[buf] + idx * 512);
        }
    };
    auto STAGE2 = [&](int buf, int step) {       // step<32: K=1024
        int k0 = step * 32;
#pragma unroll
        for (int i = 0; i < 4; ++i) {
            int idx = w * 4 + i;
            glds16(W2t + (size_t)(idx * 16 + (l >> 2)) * FF + k0 + (l & 3) * 8,
                   Bs[buf] + idx * 512);
        }
    };

    f32x4 acc[4];
#pragma unroll
    for (int j = 0; j < 4; ++j) acc[j] = (f32x4)(0.f);

    // ---- phase 1: FF1 (4 chunks x 8 steps) ----
    STAGE1(0, 0);
    for (int stage = 0; stage < 32; ++stage) {
        int cur = stage & 1;
        __syncthreads();
        if (stage + 1 < 32) STAGE1(cur ^ 1, stage + 1);
        else               STAGE2(cur ^ 1, 0);   // prefetch first FF2 stage
        s16x8 af = af1[stage & 7];
#pragma unroll
        for (int j = 0; j < 4; ++j) {
            s16x8 bf = *reinterpret_cast<const s16x8*>(
                Bs[cur] + (w * 64 + j * 16 + lr) * 32 + lg * 8);
            acc[j] = __builtin_amdgcn_mfma_f32_16x16x32_bf16(af, bf, acc[j], 0, 0, 0);
        }
        if ((stage & 7) == 7) {
            int nc = stage >> 3;
#pragma unroll
            for (int j = 0; j < 4; ++j) {
                int col = nc * 256 + w * 64 + j * 16 + lr;
                float bc = b1[col];
#pragma unroll
                for (int q = 0; q < 4; ++q)
                    fm[(lg * 4 + q) * 1032 + col] = f2b(fmaxf(acc[j][q] + bc, 0.f));
                acc[j] = (f32x4)(0.f);
            }
        }
    }

    // ---- phase 2: FF2 (32 steps), A from fm ----
    for (int step = 0; step < 32; ++step) {
        int cur = step & 1;
        __syncthreads();   // first iter: fm writes + STAGE2(0) loads complete
        if (step + 1 < 32) STAGE2(cur ^ 1, step + 1);
        s16x8 af = *reinterpret_cast<const s16x8*>(fm + lr * 1032 + step * 32 + lg * 8);
#pragma unroll
        for (int j = 0; j < 4; ++j) {
            s16x8 bf = *reinterpret_cast<const s16x8*>(
                Bs[cur] + (w * 64 + j * 16 + lr) * 32 + lg * 8);
            acc[j] = __builtin_amdgcn_mfma_f32_16x16x32_bf16(af, bf, acc[j], 0, 0, 0);
        }
    }

    // ---- epilogue: bias + residual; cross-wave LN ----
    float rsum[4] = {0.f, 0.f, 0.f, 0.f};
#pragma unroll
    for (int j = 0; j < 4; ++j) {
        int col = w * 64 + j * 16 + lr;
        float bc = b2[col];
#pragma unroll
        for (int q = 0; q < 4; ++q) {
            float x = acc[j][q] + bc + res[(size_t)(m0 + lg * 4 + q) * DD + col];
            acc[j][q] = x;
            rsum[q] += x;
        }
    }
#pragma unroll
    for (int q = 0; q < 4; ++q)
#pragma unroll
        for (int o = 1; o < 16; o <<= 1) rsum[q] += __shfl_xor(rsum[q], o);
    __syncthreads();
    if (lr == 0)
#pragma unroll
        for (int q = 0; q < 4; ++q) Red[lg * 4 + q][w] = rsum[q];
    __syncthreads();
    float mean[4];
#pragma unroll
    for (int q = 0; q < 4; ++q) {
        int row = lg * 4 + q;
        mean[q] = (Red[row][0] + Red[row][1] + Red[row][2] + Red[row][3]) * (1.0f / 256.0f);
    }
    float ssum[4] = {0.f, 0.f, 0.f, 0.f};
#pragma unroll
    for (int j = 0; j < 4; ++j)
#pragma unroll
        for (int q = 0; q < 4; ++q) {
            float d = acc[j][q] - mean[q];
            ssum[q] += d * d;
        }
#pragma unroll
    for (int q = 0; q < 4; ++q)
#pragma unroll
        for (int o = 1; o < 16; o <<= 1) ssum[q] += __shfl_xor(ssum[q], o);
    __syncthreads();
    if (lr == 0)
#pragma unroll
        for (int q = 0; q < 4; ++q) Red[lg * 4 + q][w] = ssum[q];
    __syncthreads();
    float rstd[4];
#pragma unroll
    for (int q = 0; q < 4; ++q) {
        int row = lg * 4 + q;
        float var = (Red[row][0] + Red[row][1] + Red[row][2] + Red[row][3]) * (1.0f / 256.0f);
        rstd[q] = 1.0f / sqrtf(var + 1e-5f);
    }
#pragma unroll
    for (int j = 0; j < 4; ++j) {
        int col = w * 64 + j * 16 + lr;
        float gc = g[col], bc2 = be[col];
#pragma unroll
        for (int q = 0; q < 4; ++q) {
            size_t off = (size_t)(m0 + lg * 4 + q) * DD + col;
            float v = (acc[j][q] - mean[q]) * rstd[q] * gc + bc2;
            out[off] = v;
            outb[off] = f2b(v);
        }
    }
}

// ---------------------------------------------------------------------------
extern "C" void kernel_launch(void* const* d_in, const int* in_sizes, int n_in,
                              void* d_out, int out_size, void* d_ws, size_t ws_size,
                              hipStream_t stream) {
    const float* vehicles = (const float*)d_in[0];
    const float* fleet    = (const float*)d_in[1];
    const float* Wproj    = (const float*)d_in[2];
    const float* bproj    = (const float*)d_in[3];
    const float* Wq       = (const float*)d_in[4];
    const float* Wk       = (const float*)d_in[5];
    const float* Wv       = (const float*)d_in[6];
    const float* m1w      = (const float*)d_in[7];
    const float* m1b      = (const float*)d_in[8];
    const float* m2w      = (const float*)d_in[9];
    const float* m2b      = (const float*)d_in[10];
    const float* Wo       = (const float*)d_in[11];
    const float* bo       = (const float*)d_in[12];
    const float* n1_g     = (const float*)d_in[13];
    const float* n1_b     = (const float*)d_in[14];
    const float* ff1_w    = (const float*)d_in[15];
    const float* ff1_b    = (const float*)d_in[16];
    const float* ff2_w    = (const float*)d_in[17];
    const float* ff2_b    = (const float*)d_in[18];
    const float* n2_g     = (const float*)d_in[19];
    const float* n2_b     = (const float*)d_in[20];

    const size_t MROWS = (size_t)NB * LL;           // 8192
    const size_t HSZ   = MROWS * DD;                // 2,097,152

    float* ws = (float*)d_ws;
    float* h   = ws;                                 // HSZ f32
    float* qh  = h + HSZ;                            // HSZ f32
    float* kh  = qh + HSZ;                           // HSZ f32
    float* vh  = kh + HSZ;                           // HSZ f32
    unsigned short* hb = (unsigned short*)(vh + HSZ);               // HSZ bf16
    unsigned short* Wt = hb + HSZ;                                  // 3*WLS bf16
    unsigned long long* idx8 = (unsigned long long*)(Wt + 3 * WLS); // 8192 u64

    // preprocessing: one dispatch
    uber_pre<<<6400, 256, 0, stream>>>(vehicles, Wproj, bproj, h, hb,
                                       fleet, idx8,
                                       Wq, Wk, Wv, Wo, ff1_w, ff2_w, Wt);

    dim3 gqkv(12, 128);  // QKV: 64x64 tiles, N=768 -> 1536 blocks

    for (int i = 0; i < LC; ++i) {
        const unsigned short* wt = Wt + (size_t)i * WLS;

        gg<64, 64, 2, 2, 2><<<gqkv, 256, 0, stream>>>(
            hb, wt, nullptr, nullptr, qh, kh, vh, DD, 768);

        attnwo_ln<<<512, 256, 0, stream>>>(
            wt + 196608,
            qh, kh, vh, fleet, idx8,
            m1w + (size_t)i * HH * 2 * MS, m1b + (size_t)i * HH * MS,
            m2w + (size_t)i * HH * MS,     m2b + (size_t)i * HH,
            bo + (size_t)i * DD,
            h, n1_g + (size_t)i * DD, n1_b + (size_t)i * DD, h, hb);

        float* dst = (i == LC - 1) ? (float*)d_out : h;
        ff_ln<<<512, 256, 0, stream>>>(
            hb, wt + 262144, wt + 524288,
            ff1_b + (size_t)i * FF, ff2_b + (size_t)i * DD,
            h, n2_g + (size_t)i * DD, n2_b + (size_t)i * DD, dst, hb);
    }
}

// Round 18
// 242.893 us; speedup vs baseline: 1.0009x; 1.0009x over previous
//
#include <hip/hip_runtime.h>
#include <math.h>

// Problem constants
#define NB 64    // N batch
#define LL 128   // L
#define DV 16
#define DD 256   // D
#define HH 8     // heads
#define DK 32    // D/H
#define FF 1024
#define LC 3
#define KNN 6
#define MS 16
#define WLS 786432   // per-layer transposed-weight stride (elems)
#define FMS 1064     // fm LDS row stride (shorts): 532 dwords = 20 mod 32 -> 2-way only

typedef __attribute__((ext_vector_type(8))) short s16x8;   // 8 bf16 (4 VGPR)
typedef __attribute__((ext_vector_type(4))) float f32x4;   // MFMA acc

static __device__ inline unsigned short f2b(float x) {
    union { float f; unsigned int u; } v; v.f = x;
    unsigned int r = (v.u + 0x7FFFu + ((v.u >> 16) & 1u)) >> 16;
    return (unsigned short)r;
}

// global -> LDS direct (16B per lane; dest = wave-uniform base + lane*16)
static __device__ __forceinline__ void glds16(const void* g, void* l) {
    __builtin_amdgcn_global_load_lds(
        (const __attribute__((address_space(1))) void*)g,
        (__attribute__((address_space(3))) void*)l, 16, 0, 0);
}

// ---------------------------------------------------------------------------
// Uber preprocessing: [0,2048) proj | [2048,4096) knn | [4096,6400) transpose
// ---------------------------------------------------------------------------
__global__ __launch_bounds__(256)
void uber_pre(const float* __restrict__ veh, const float* __restrict__ Wp,
              const float* __restrict__ bp, float* __restrict__ h,
              unsigned short* __restrict__ hb,
              const float* __restrict__ edges, unsigned long long* __restrict__ idx8,
              const float* __restrict__ Wq, const float* __restrict__ Wk,
              const float* __restrict__ Wv, const float* __restrict__ Wo,
              const float* __restrict__ f1, const float* __restrict__ f2,
              unsigned short* __restrict__ Wt) {
    int bx = blockIdx.x;
    if (bx < 2048) {
        int m = bx * 4 + (threadIdx.x >> 6);
        int l = threadIdx.x & 63;
        int c0 = l * 4;
        const float4* w4 = reinterpret_cast<const float4*>(Wp);
        float4 a = *reinterpret_cast<const float4*>(bp + c0);
        const float* vr = veh + (size_t)m * DV;
#pragma unroll
        for (int t = 0; t < DV; ++t) {
            float vt = vr[t];
            float4 wv = w4[t * 64 + l];
            a.x += vt * wv.x; a.y += vt * wv.y; a.z += vt * wv.z; a.w += vt * wv.w;
        }
        *reinterpret_cast<float4*>(h + (size_t)m * DD + c0) = a;
        ushort4 u; u.x = f2b(a.x); u.y = f2b(a.y); u.z = f2b(a.z); u.w = f2b(a.w);
        *reinterpret_cast<ushort4*>(hb + (size_t)m * DD + c0) = u;
        return;
    }
    if (bx < 4096) {
        int row = (bx - 2048) * 4 + (threadIdx.x >> 6);
        int lane = threadIdx.x & 63;
        const float* dr = edges + (size_t)row * LL * 4;
        float v0 = dr[lane * 4], v1 = dr[(lane + 64) * 4];
        int i0 = lane, i1 = lane + 64;
        unsigned long long packed = 0;
#pragma unroll
        for (int k = 0; k < KNN; ++k) {
            float v; int i;
            if (v1 < v0) { v = v1; i = i1; } else { v = v0; i = i0; }
#pragma unroll
            for (int o = 1; o < 64; o <<= 1) {
                float ov = __shfl_xor(v, o);
                int oi = __shfl_xor(i, o);
                if (ov < v || (ov == v && oi < i)) { v = ov; i = oi; }
            }
            packed |= (unsigned long long)i << (k * 8);
            if (i == i0) v0 = 3.4e38f;
            if (i == i1) v1 = 3.4e38f;
        }
        if (lane == 0) idx8[row] = packed;
        return;
    }
    {
        int t = bx - 4096;            // < 2304
        int ll = t / 768, r = t % 768;
        int w, tile, K, N;
        if (r < 256)      { w = r >> 6; tile = r & 63;  K = DD; N = DD; }
        else if (r < 512) { w = 4; tile = r - 256;      K = DD; N = FF; }
        else              { w = 5; tile = r - 512;      K = FF; N = DD; }
        const float* src = (w == 0) ? Wq : (w == 1) ? Wk : (w == 2) ? Wv :
                           (w == 3) ? Wo : (w == 4) ? f1 : f2;
        src += (size_t)ll * K * N;
        long off = (w == 4) ? 262144L : (w == 5) ? 524288L : (long)w * 65536L;
        unsigned short* dst = Wt + (size_t)ll * WLS + off;
        int ntx = N >> 5;
        int n0 = (tile % ntx) * 32, k0 = (tile / ntx) * 32;
        int tx = threadIdx.x & 31, ty = threadIdx.x >> 5;
        __shared__ float T[32][33];
#pragma unroll
        for (int rr = 0; rr < 4; ++rr)
            T[ty + rr * 8][tx] = src[(size_t)(k0 + ty + rr * 8) * N + n0 + tx];
        __syncthreads();
#pragma unroll
        for (int rr = 0; rr < 4; ++rr)
            dst[(size_t)(n0 + ty + rr * 8) * K + k0 + tx] = f2b(T[tx][ty + rr * 8]);
    }
}

// ---------------------------------------------------------------------------
// Unified MFMA GEMM, double-buffered: issue next K-step's global_load_lds
// BEFORE computing current step; ONE barrier per step.
// MODE 2: QKV scatter -> f32 head-major Oq/Ok/Ov (no bias).
// ---------------------------------------------------------------------------
template <int BM, int BN, int WR, int WC, int MODE>
__global__ __launch_bounds__(256)
void gg(const unsigned short* __restrict__ A, const unsigned short* __restrict__ Bt,
        const float* __restrict__ bias, unsigned short* __restrict__ Cb,
        float* __restrict__ Oq, float* __restrict__ Ok, float* __restrict__ Ov,
        int K, int N) {
    constexpr int MI = BM / (WR * 16);
    constexpr int NJ = BN / (WC * 16);
    __shared__ unsigned short As[2][BM * 32];
    __shared__ unsigned short Bs[2][BN * 32];
    int tid = threadIdx.x;
    int w = tid >> 6, l = tid & 63;
    int lr = l & 15, lg = l >> 4;
    int wr = w % WR, wc = w / WR;
    int m0 = blockIdx.y * BM, n0 = blockIdx.x * BN;
    int row = tid >> 2, seg = tid & 3;

    auto STAGE = [&](int buf, int k0) {
#pragma unroll
        for (int r = 0; r < BM / 64; ++r)
            glds16(A + (size_t)(m0 + r * 64 + row) * K + k0 + seg * 8,
                   As[buf] + r * 2048 + w * 512);
#pragma unroll
        for (int r = 0; r < BN / 64; ++r)
            glds16(Bt + (size_t)(n0 + r * 64 + row) * K + k0 + seg * 8,
                   Bs[buf] + r * 2048 + w * 512);
    };

    f32x4 acc[MI][NJ];
#pragma unroll
    for (int i = 0; i < MI; ++i)
#pragma unroll
        for (int j = 0; j < NJ; ++j) acc[i][j] = (f32x4)(0.f);

    STAGE(0, 0);
    int nsteps = K >> 5;
    for (int step = 0; step < nsteps; ++step) {
        int cur = step & 1;
        __syncthreads();   // drains buf[cur] loads; prior reads of buf[cur^1] done
        if (step + 1 < nsteps) STAGE(cur ^ 1, (step + 1) * 32);
        s16x8 af[MI], bf[NJ];
#pragma unroll
        for (int i = 0; i < MI; ++i)
            af[i] = *reinterpret_cast<const s16x8*>(
                As[cur] + (wr * MI * 16 + i * 16 + lr) * 32 + lg * 8);
#pragma unroll
        for (int j = 0; j < NJ; ++j)
            bf[j] = *reinterpret_cast<const s16x8*>(
                Bs[cur] + (wc * NJ * 16 + j * 16 + lr) * 32 + lg * 8);
#pragma unroll
        for (int i = 0; i < MI; ++i)
#pragma unroll
            for (int j = 0; j < NJ; ++j)
                acc[i][j] = __builtin_amdgcn_mfma_f32_16x16x32_bf16(af[i], bf[j], acc[i][j], 0, 0, 0);
    }

    if constexpr (MODE == 2) {
        int s = n0 >> 8;          // 0=q,1=k,2=v (64-wide tiles never cross 256)
        float* dst = (s == 0) ? Oq : (s == 1) ? Ok : Ov;
#pragma unroll
        for (int i = 0; i < MI; ++i)
#pragma unroll
            for (int j = 0; j < NJ; ++j) {
                int cc = (n0 & 255) + wc * NJ * 16 + j * 16 + lr;
                int hh = cc >> 5, dk = cc & 31;
                int grow = m0 + wr * MI * 16 + i * 16 + lg * 4;
                int nn = grow >> 7, rl = grow & 127;
                size_t ho = ((size_t)(nn * HH + hh) * LL + rl) * DK + dk;
#pragma unroll
                for (int q = 0; q < 4; ++q)
                    dst[ho + (size_t)q * DK] = acc[i][j][q];
            }
    } else {
#pragma unroll
        for (int i = 0; i < MI; ++i)
#pragma unroll
            for (int j = 0; j < NJ; ++j) {
                int col = n0 + wc * NJ * 16 + j * 16 + lr;
                float bc = bias[col];
#pragma unroll
                for (int q = 0; q < 4; ++q) {
                    int r = m0 + wr * MI * 16 + i * 16 + lg * 4 + q;
                    float v = fmaxf(acc[i][j][q] + bc, 0.f);
                    Cb[(size_t)r * N + col] = f2b(v);
                }
            }
    }
}

// ---------------------------------------------------------------------------
// Fused sparse-attention + Wo GEMM(16x256) + bias + residual + LayerNorm.
// 512 blocks, 4 waves; wave w owns cols w*64..+63. Double-buffered B staging.
// ---------------------------------------------------------------------------
__global__ __launch_bounds__(256)
void attnwo_ln(const unsigned short* __restrict__ Bt,
               const float* __restrict__ qh, const float* __restrict__ kh,
               const float* __restrict__ vh, const float* __restrict__ edges,
               const unsigned long long* __restrict__ idx8,
               const float* __restrict__ m1w, const float* __restrict__ m1b,
               const float* __restrict__ m2w, const float* __restrict__ m2b,
               const float* __restrict__ bias, const float* __restrict__ res,
               const float* __restrict__ g, const float* __restrict__ be,
               float* __restrict__ out, unsigned short* __restrict__ outb) {
    constexpr int KK = 256;
    __shared__ unsigned short Afull[16 * 264];   // attn-built A (bf16)
    __shared__ unsigned short Bs[2][256 * 32];   // 2 x 16 KB
    __shared__ float Red[16][4];
    int tid = threadIdx.x;
    int w = tid >> 6, l = tid & 63;
    int lr = l & 15, lg = l >> 4;
    int m0 = blockIdx.x * 16;

    {
        // ---- sparse kNN attention prologue: 128 tasks x 2 threads ----
        int task = tid >> 1, sub = tid & 1;
        int rl = task & 15, hh = task >> 4;
        int n = m0 >> 7, r = (m0 & 127) + rl;
        int bh = n * HH + hh;
        const float scale = 0.17677669529663687f;   // 1/sqrt(32)
        const float* w0g = m1w + (hh * 2 + 0) * MS;
        const float* w1g = m1w + (hh * 2 + 1) * MS;
        const float* b1g = m1b + hh * MS;
        const float* w2g = m2w + hh * MS;
        float b2v = m2b[hh];

        const float4* qr = reinterpret_cast<const float4*>(
            qh + ((size_t)bh * LL + r) * DK) + sub * 4;
        float4 q[4];
#pragma unroll
        for (int j = 0; j < 4; ++j) q[j] = qr[j];

        unsigned long long pk = idx8[(size_t)n * LL + r];
        const float* kbase = kh + (size_t)bh * LL * DK;
        const float* vbase = vh + (size_t)bh * LL * DK;
        const float* erow = edges + (size_t)(n * LL + r) * LL * 4;

        int col[KNN];
#pragma unroll
        for (int k = 0; k < KNN; ++k) col[k] = (int)((pk >> (k * 8)) & 0xFF);

        float e[KNN];
        float mx = -3.4e38f;
#pragma unroll
        for (int k = 0; k < KNN; ++k) {
            const float4* kr = reinterpret_cast<const float4*>(
                kbase + (size_t)col[k] * DK) + sub * 4;
            float d = 0.f;
#pragma unroll
            for (int j = 0; j < 4; ++j) {
                float4 kv = kr[j];
                d += q[j].x * kv.x + q[j].y * kv.y + q[j].z * kv.z + q[j].w * kv.w;
            }
            d += __shfl_xor(d, 1);      // merge the two 16-dim halves
            d *= scale;
            float cst = erow[col[k] * 4];
            float s = b2v;
#pragma unroll
            for (int m = 0; m < MS; ++m)
                s += fmaxf(d * w0g[m] + cst * w1g[m] + b1g[m], 0.f) * w2g[m];
            e[k] = s;
            mx = fmaxf(mx, s);
        }
        float sum = 0.f;
#pragma unroll
        for (int k = 0; k < KNN; ++k) { e[k] = __expf(e[k] - mx); sum += e[k]; }
        float inv = 1.f / sum;

        float4 att[4];
#pragma unroll
        for (int j = 0; j < 4; ++j) att[j] = make_float4(0.f, 0.f, 0.f, 0.f);
#pragma unroll
        for (int k = 0; k < KNN; ++k) {
            float wgt = e[k] * inv;
            const float4* vr = reinterpret_cast<const float4*>(
                vbase + (size_t)col[k] * DK) + sub * 4;
#pragma unroll
            for (int j = 0; j < 4; ++j) {
                float4 vv = vr[j];
                att[j].x += wgt * vv.x; att[j].y += wgt * vv.y;
                att[j].z += wgt * vv.z; att[j].w += wgt * vv.w;
            }
        }
        unsigned short* arow = Afull + rl * 264 + hh * DK + sub * 16;
#pragma unroll
        for (int j = 0; j < 4; ++j) {
            ushort4 u;
            u.x = f2b(att[j].x); u.y = f2b(att[j].y);
            u.z = f2b(att[j].z); u.w = f2b(att[j].w);
            *reinterpret_cast<ushort4*>(arow + j * 4) = u;
        }
    }

    auto STAGE = [&](int buf, int k0) {
#pragma unroll
        for (int i = 0; i < 4; ++i) {
            int idx = w * 4 + i;    // 16 wave-loads cover 256 B-rows
            glds16(Bt + (size_t)(idx * 16 + (l >> 2)) * KK + k0 + (l & 3) * 8,
                   Bs[buf] + idx * 512);
        }
    };

    f32x4 acc[4];
#pragma unroll
    for (int j = 0; j < 4; ++j) acc[j] = (f32x4)(0.f);

    STAGE(0, 0);
    constexpr int NSTEPS = KK >> 5;
    for (int step = 0; step < NSTEPS; ++step) {
        int cur = step & 1;
        __syncthreads();
        if (step + 1 < NSTEPS) STAGE(cur ^ 1, (step + 1) * 32);
        s16x8 af = *reinterpret_cast<const s16x8*>(Afull + lr * 264 + step * 32 + lg * 8);
#pragma unroll
        for (int j = 0; j < 4; ++j) {
            s16x8 bf = *reinterpret_cast<const s16x8*>(
                Bs[cur] + (w * 64 + j * 16 + lr) * 32 + lg * 8);
            acc[j] = __builtin_amdgcn_mfma_f32_16x16x32_bf16(af, bf, acc[j], 0, 0, 0);
        }
    }

    // ---- epilogue: bias + residual; cross-wave LN ----
    float rsum[4] = {0.f, 0.f, 0.f, 0.f};
#pragma unroll
    for (int j = 0; j < 4; ++j) {
        int col = w * 64 + j * 16 + lr;
        float bc = bias[col];
#pragma unroll
        for (int q = 0; q < 4; ++q) {
            float x = acc[j][q] + bc + res[(size_t)(m0 + lg * 4 + q) * DD + col];
            acc[j][q] = x;
            rsum[q] += x;
        }
    }
#pragma unroll
    for (int q = 0; q < 4; ++q)
#pragma unroll
        for (int o = 1; o < 16; o <<= 1) rsum[q] += __shfl_xor(rsum[q], o);
    __syncthreads();
    if (lr == 0)
#pragma unroll
        for (int q = 0; q < 4; ++q) Red[lg * 4 + q][w] = rsum[q];
    __syncthreads();
    float mean[4];
#pragma unroll
    for (int q = 0; q < 4; ++q) {
        int row = lg * 4 + q;
        mean[q] = (Red[row][0] + Red[row][1] + Red[row][2] + Red[row][3]) * (1.0f / 256.0f);
    }
    float ssum[4] = {0.f, 0.f, 0.f, 0.f};
#pragma unroll
    for (int j = 0; j < 4; ++j)
#pragma unroll
        for (int q = 0; q < 4; ++q) {
            float d = acc[j][q] - mean[q];
            ssum[q] += d * d;
        }
#pragma unroll
    for (int q = 0; q < 4; ++q)
#pragma unroll
        for (int o = 1; o < 16; o <<= 1) ssum[q] += __shfl_xor(ssum[q], o);
    __syncthreads();
    if (lr == 0)
#pragma unroll
        for (int q = 0; q < 4; ++q) Red[lg * 4 + q][w] = ssum[q];
    __syncthreads();
    float rstd[4];
#pragma unroll
    for (int q = 0; q < 4; ++q) {
        int row = lg * 4 + q;
        float var = (Red[row][0] + Red[row][1] + Red[row][2] + Red[row][3]) * (1.0f / 256.0f);
        rstd[q] = 1.0f / sqrtf(var + 1e-5f);
    }
#pragma unroll
    for (int j = 0; j < 4; ++j) {
        int col = w * 64 + j * 16 + lr;
        float gc = g[col], bc2 = be[col];
#pragma unroll
        for (int q = 0; q < 4; ++q) {
            size_t off = (size_t)(m0 + lg * 4 + q) * DD + col;
            float v = (acc[j][q] - mean[q]) * rstd[q] * gc + bc2;
            out[off] = v;
            outb[off] = f2b(v);
        }
    }
}

// ---------------------------------------------------------------------------
// Fused FF1(relu) + FF2 + bias + residual + LayerNorm. 512 blocks x 16 rows.
// fm stride FMS=1064 shorts (532 dwords = 20 mod 32): 2-way bank aliasing
// only (free) on both the relu writes and the FF2 A-frag reads.
// ---------------------------------------------------------------------------
__global__ __launch_bounds__(256)
void ff_ln(const unsigned short* __restrict__ hb_in,
           const unsigned short* __restrict__ W1t, const unsigned short* __restrict__ W2t,
           const float* __restrict__ b1, const float* __restrict__ b2,
           const float* __restrict__ res, const float* __restrict__ g,
           const float* __restrict__ be,
           float* __restrict__ out, unsigned short* __restrict__ outb) {
    __shared__ unsigned short fm[16 * FMS];      // ~34 KB
    __shared__ unsigned short Bs[2][256 * 32];   // 32 KB
    __shared__ float Red[16][4];
    int tid = threadIdx.x;
    int w = tid >> 6, l = tid & 63;
    int lr = l & 15, lg = l >> 4;
    int m0 = blockIdx.x * 16;

    // preload FF1 A-frags (K=256, 8 steps) into registers — reused per chunk
    s16x8 af1[8];
    {
        const unsigned short* arow = hb_in + (size_t)(m0 + lr) * DD + lg * 8;
#pragma unroll
        for (int s = 0; s < 8; ++s)
            af1[s] = *reinterpret_cast<const s16x8*>(arow + s * 32);
    }

    auto STAGE1 = [&](int buf, int stage) {      // stage<32: chunk=stage>>3
        int chunk = stage >> 3, k0 = (stage & 7) * 32;
        const unsigned short* base = W1t + (size_t)(chunk * 256) * DD;
#pragma unroll
        for (int i = 0; i < 4; ++i) {
            int idx = w * 4 + i;
            glds16(base + (size_t)(idx * 16 + (l >> 2)) * DD + k0 + (l & 3) * 8,
                   Bs[buf] + idx * 512);
        }
    };
    auto STAGE2 = [&](int buf, int step) {       // step<32: K=1024
        int k0 = step * 32;
#pragma unroll
        for (int i = 0; i < 4; ++i) {
            int idx = w * 4 + i;
            glds16(W2t + (size_t)(idx * 16 + (l >> 2)) * FF + k0 + (l & 3) * 8,
                   Bs[buf] + idx * 512);
        }
    };

    f32x4 acc[4];
#pragma unroll
    for (int j = 0; j < 4; ++j) acc[j] = (f32x4)(0.f);

    // ---- phase 1: FF1 (4 chunks x 8 steps) ----
    STAGE1(0, 0);
    for (int stage = 0; stage < 32; ++stage) {
        int cur = stage & 1;
        __syncthreads();
        if (stage + 1 < 32) STAGE1(cur ^ 1, stage + 1);
        else               STAGE2(cur ^ 1, 0);   // prefetch first FF2 stage
        s16x8 af = af1[stage & 7];
#pragma unroll
        for (int j = 0; j < 4; ++j) {
            s16x8 bf = *reinterpret_cast<const s16x8*>(
                Bs[cur] + (w * 64 + j * 16 + lr) * 32 + lg * 8);
            acc[j] = __builtin_amdgcn_mfma_f32_16x16x32_bf16(af, bf, acc[j], 0, 0, 0);
        }
        if ((stage & 7) == 7) {
            int nc = stage >> 3;
#pragma unroll
            for (int j = 0; j < 4; ++j) {
                int col = nc * 256 + w * 64 + j * 16 + lr;
                float bc = b1[col];
#pragma unroll
                for (int q = 0; q < 4; ++q)
                    fm[(lg * 4 + q) * FMS + col] = f2b(fmaxf(acc[j][q] + bc, 0.f));
                acc[j] = (f32x4)(0.f);
            }
        }
    }

    // ---- phase 2: FF2 (32 steps), A from fm ----
    for (int step = 0; step < 32; ++step) {
        int cur = step & 1;
        __syncthreads();   // first iter: fm writes + STAGE2(0) loads complete
        if (step + 1 < 32) STAGE2(cur ^ 1, step + 1);
        s16x8 af = *reinterpret_cast<const s16x8*>(fm + lr * FMS + step * 32 + lg * 8);
#pragma unroll
        for (int j = 0; j < 4; ++j) {
            s16x8 bf = *reinterpret_cast<const s16x8*>(
                Bs[cur] + (w * 64 + j * 16 + lr) * 32 + lg * 8);
            acc[j] = __builtin_amdgcn_mfma_f32_16x16x32_bf16(af, bf, acc[j], 0, 0, 0);
        }
    }

    // ---- epilogue: bias + residual; cross-wave LN ----
    float rsum[4] = {0.f, 0.f, 0.f, 0.f};
#pragma unroll
    for (int j = 0; j < 4; ++j) {
        int col = w * 64 + j * 16 + lr;
        float bc = b2[col];
#pragma unroll
        for (int q = 0; q < 4; ++q) {
            float x = acc[j][q] + bc + res[(size_t)(m0 + lg * 4 + q) * DD + col];
            acc[j][q] = x;
            rsum[q] += x;
        }
    }
#pragma unroll
    for (int q = 0; q < 4; ++q)
#pragma unroll
        for (int o = 1; o < 16; o <<= 1) rsum[q] += __shfl_xor(rsum[q], o);
    __syncthreads();
    if (lr == 0)
#pragma unroll
        for (int q = 0; q < 4; ++q) Red[lg * 4 + q][w] = rsum[q];
    __syncthreads();
    float mean[4];
#pragma unroll
    for (int q = 0; q < 4; ++q) {
        int row = lg * 4 + q;
        mean[q] = (Red[row][0] + Red[row][1] + Red[row][2] + Red[row][3]) * (1.0f / 256.0f);
    }
    float ssum[4] = {0.f, 0.f, 0.f, 0.f};
#pragma unroll
    for (int j = 0; j < 4; ++j)
#pragma unroll
        for (int q = 0; q < 4; ++q) {
            float d = acc[j][q] - mean[q];
            ssum[q] += d * d;
        }
#pragma unroll
    for (int q = 0; q < 4; ++q)
#pragma unroll
        for (int o = 1; o < 16; o <<= 1) ssum[q] += __shfl_xor(ssum[q], o);
    __syncthreads();
    if (lr == 0)
#pragma unroll
        for (int q = 0; q < 4; ++q) Red[lg * 4 + q][w] = ssum[q];
    __syncthreads();
    float rstd[4];
#pragma unroll
    for (int q = 0; q < 4; ++q) {
        int row = lg * 4 + q;
        float var = (Red[row][0] + Red[row][1] + Red[row][2] + Red[row][3]) * (1.0f / 256.0f);
        rstd[q] = 1.0f / sqrtf(var + 1e-5f);
    }
#pragma unroll
    for (int j = 0; j < 4; ++j) {
        int col = w * 64 + j * 16 + lr;
        float gc = g[col], bc2 = be[col];
#pragma unroll
        for (int q = 0; q < 4; ++q) {
            size_t off = (size_t)(m0 + lg * 4 + q) * DD + col;
            float v = (acc[j][q] - mean[q]) * rstd[q] * gc + bc2;
            out[off] = v;
            outb[off] = f2b(v);
        }
    }
}

// ---------------------------------------------------------------------------
extern "C" void kernel_launch(void* const* d_in, const int* in_sizes, int n_in,
                              void* d_out, int out_size, void* d_ws, size_t ws_size,
                              hipStream_t stream) {
    const float* vehicles = (const float*)d_in[0];
    const float* fleet    = (const float*)d_in[1];
    const float* Wproj    = (const float*)d_in[2];
    const float* bproj    = (const float*)d_in[3];
    const float* Wq       = (const float*)d_in[4];
    const float* Wk       = (const float*)d_in[5];
    const float* Wv       = (const float*)d_in[6];
    const float* m1w      = (const float*)d_in[7];
    const float* m1b      = (const float*)d_in[8];
    const float* m2w      = (const float*)d_in[9];
    const float* m2b      = (const float*)d_in[10];
    const float* Wo       = (const float*)d_in[11];
    const float* bo       = (const float*)d_in[12];
    const float* n1_g     = (const float*)d_in[13];
    const float* n1_b     = (const float*)d_in[14];
    const float* ff1_w    = (const float*)d_in[15];
    const float* ff1_b    = (const float*)d_in[16];
    const float* ff2_w    = (const float*)d_in[17];
    const float* ff2_b    = (const float*)d_in[18];
    const float* n2_g     = (const float*)d_in[19];
    const float* n2_b     = (const float*)d_in[20];

    const size_t MROWS = (size_t)NB * LL;           // 8192
    const size_t HSZ   = MROWS * DD;                // 2,097,152

    float* ws = (float*)d_ws;
    float* h   = ws;                                 // HSZ f32
    float* qh  = h + HSZ;                            // HSZ f32
    float* kh  = qh + HSZ;                           // HSZ f32
    float* vh  = kh + HSZ;                           // HSZ f32
    unsigned short* hb = (unsigned short*)(vh + HSZ);               // HSZ bf16
    unsigned short* Wt = hb + HSZ;                                  // 3*WLS bf16
    unsigned long long* idx8 = (unsigned long long*)(Wt + 3 * WLS); // 8192 u64

    // preprocessing: one dispatch
    uber_pre<<<6400, 256, 0, stream>>>(vehicles, Wproj, bproj, h, hb,
                                       fleet, idx8,
                                       Wq, Wk, Wv, Wo, ff1_w, ff2_w, Wt);

    dim3 gqkv(12, 128);  // QKV: 64x64 tiles, N=768 -> 1536 blocks

    for (int i = 0; i < LC; ++i) {
        const unsigned short* wt = Wt + (size_t)i * WLS;

        gg<64, 64, 2, 2, 2><<<gqkv, 256, 0, stream>>>(
            hb, wt, nullptr, nullptr, qh, kh, vh, DD, 768);

        attnwo_ln<<<512, 256, 0, stream>>>(
            wt + 196608,
            qh, kh, vh, fleet, idx8,
            m1w + (size_t)i * HH * 2 * MS, m1b + (size_t)i * HH * MS,
            m2w + (size_t)i * HH * MS,     m2b + (size_t)i * HH,
            bo + (size_t)i * DD,
            h, n1_g + (size_t)i * DD, n1_b + (size_t)i * DD, h, hb);

        float* dst = (i == LC - 1) ? (float*)d_out : h;
        ff_ln<<<512, 256, 0, stream>>>(
            hb, wt + 262144, wt + 524288,
            ff1_b + (size_t)i * FF, ff2_b + (size_t)i * DD,
            h, n2_g + (size_t)i * DD, n2_b + (size_t)i * DD, dst, hb);
    }
}

// Round 19
// 223.640 us; speedup vs baseline: 1.0871x; 1.0861x over previous
//
#include <hip/hip_runtime.h>
#include <math.h>

// Problem constants
#define NB 64    // N batch
#define LL 128   // L
#define DV 16
#define DD 256   // D
#define HH 8     // heads
#define DK 32    // D/H
#define FF 1024
#define LC 3
#define KNN 6
#define MS 16
#define WLS 786432   // per-layer transposed-weight stride (elems)

typedef __attribute__((ext_vector_type(8))) short s16x8;   // 8 bf16 (4 VGPR)
typedef __attribute__((ext_vector_type(4))) float f32x4;   // MFMA acc

static __device__ inline unsigned short f2b(float x) {
    union { float f; unsigned int u; } v; v.f = x;
    unsigned int r = (v.u + 0x7FFFu + ((v.u >> 16) & 1u)) >> 16;
    return (unsigned short)r;
}

// global -> LDS direct (16B per lane; dest = wave-uniform base + lane*16)
static __device__ __forceinline__ void glds16(const void* g, void* l) {
    __builtin_amdgcn_global_load_lds(
        (const __attribute__((address_space(1))) void*)g,
        (__attribute__((address_space(3))) void*)l, 16, 0, 0);
}

// ---------------------------------------------------------------------------
// Uber preprocessing: [0,2048) proj | [2048,4096) knn | [4096,6400) transpose
// ---------------------------------------------------------------------------
__global__ __launch_bounds__(256)
void uber_pre(const float* __restrict__ veh, const float* __restrict__ Wp,
              const float* __restrict__ bp, float* __restrict__ h,
              unsigned short* __restrict__ hb,
              const float* __restrict__ edges, unsigned long long* __restrict__ idx8,
              const float* __restrict__ Wq, const float* __restrict__ Wk,
              const float* __restrict__ Wv, const float* __restrict__ Wo,
              const float* __restrict__ f1, const float* __restrict__ f2,
              unsigned short* __restrict__ Wt) {
    int bx = blockIdx.x;
    if (bx < 2048) {
        int m = bx * 4 + (threadIdx.x >> 6);
        int l = threadIdx.x & 63;
        int c0 = l * 4;
        const float4* w4 = reinterpret_cast<const float4*>(Wp);
        float4 a = *reinterpret_cast<const float4*>(bp + c0);
        const float* vr = veh + (size_t)m * DV;
#pragma unroll
        for (int t = 0; t < DV; ++t) {
            float vt = vr[t];
            float4 wv = w4[t * 64 + l];
            a.x += vt * wv.x; a.y += vt * wv.y; a.z += vt * wv.z; a.w += vt * wv.w;
        }
        *reinterpret_cast<float4*>(h + (size_t)m * DD + c0) = a;
        ushort4 u; u.x = f2b(a.x); u.y = f2b(a.y); u.z = f2b(a.z); u.w = f2b(a.w);
        *reinterpret_cast<ushort4*>(hb + (size_t)m * DD + c0) = u;
        return;
    }
    if (bx < 4096) {
        int row = (bx - 2048) * 4 + (threadIdx.x >> 6);
        int lane = threadIdx.x & 63;
        const float* dr = edges + (size_t)row * LL * 4;
        float v0 = dr[lane * 4], v1 = dr[(lane + 64) * 4];
        int i0 = lane, i1 = lane + 64;
        unsigned long long packed = 0;
#pragma unroll
        for (int k = 0; k < KNN; ++k) {
            float v; int i;
            if (v1 < v0) { v = v1; i = i1; } else { v = v0; i = i0; }
#pragma unroll
            for (int o = 1; o < 64; o <<= 1) {
                float ov = __shfl_xor(v, o);
                int oi = __shfl_xor(i, o);
                if (ov < v || (ov == v && oi < i)) { v = ov; i = oi; }
            }
            packed |= (unsigned long long)i << (k * 8);
            if (i == i0) v0 = 3.4e38f;
            if (i == i1) v1 = 3.4e38f;
        }
        if (lane == 0) idx8[row] = packed;
        return;
    }
    {
        int t = bx - 4096;            // < 2304
        int ll = t / 768, r = t % 768;
        int w, tile, K, N;
        if (r < 256)      { w = r >> 6; tile = r & 63;  K = DD; N = DD; }
        else if (r < 512) { w = 4; tile = r - 256;      K = DD; N = FF; }
        else              { w = 5; tile = r - 512;      K = FF; N = DD; }
        const float* src = (w == 0) ? Wq : (w == 1) ? Wk : (w == 2) ? Wv :
                           (w == 3) ? Wo : (w == 4) ? f1 : f2;
        src += (size_t)ll * K * N;
        long off = (w == 4) ? 262144L : (w == 5) ? 524288L : (long)w * 65536L;
        unsigned short* dst = Wt + (size_t)ll * WLS + off;
        int ntx = N >> 5;
        int n0 = (tile % ntx) * 32, k0 = (tile / ntx) * 32;
        int tx = threadIdx.x & 31, ty = threadIdx.x >> 5;
        __shared__ float T[32][33];
#pragma unroll
        for (int rr = 0; rr < 4; ++rr)
            T[ty + rr * 8][tx] = src[(size_t)(k0 + ty + rr * 8) * N + n0 + tx];
        __syncthreads();
#pragma unroll
        for (int rr = 0; rr < 4; ++rr)
            dst[(size_t)(n0 + ty + rr * 8) * K + k0 + tx] = f2b(T[tx][ty + rr * 8]);
    }
}

// ---------------------------------------------------------------------------
// Unified MFMA GEMM, double-buffered: issue next K-step's global_load_lds
// BEFORE computing current step; ONE barrier per step.
// MODE 1: bf16 out + bias + relu (FF1). MODE 2: QKV scatter (no bias).
// ---------------------------------------------------------------------------
template <int BM, int BN, int WR, int WC, int MODE>
__global__ __launch_bounds__(256)
void gg(const unsigned short* __restrict__ A, const unsigned short* __restrict__ Bt,
        const float* __restrict__ bias, unsigned short* __restrict__ Cb,
        float* __restrict__ Oq, float* __restrict__ Ok, float* __restrict__ Ov,
        int K, int N) {
    constexpr int MI = BM / (WR * 16);
    constexpr int NJ = BN / (WC * 16);
    __shared__ unsigned short As[2][BM * 32];
    __shared__ unsigned short Bs[2][BN * 32];
    int tid = threadIdx.x;
    int w = tid >> 6, l = tid & 63;
    int lr = l & 15, lg = l >> 4;
    int wr = w % WR, wc = w / WR;
    int m0 = blockIdx.y * BM, n0 = blockIdx.x * BN;
    int row = tid >> 2, seg = tid & 3;

    auto STAGE = [&](int buf, int k0) {
#pragma unroll
        for (int r = 0; r < BM / 64; ++r)
            glds16(A + (size_t)(m0 + r * 64 + row) * K + k0 + seg * 8,
                   As[buf] + r * 2048 + w * 512);
#pragma unroll
        for (int r = 0; r < BN / 64; ++r)
            glds16(Bt + (size_t)(n0 + r * 64 + row) * K + k0 + seg * 8,
                   Bs[buf] + r * 2048 + w * 512);
    };

    f32x4 acc[MI][NJ];
#pragma unroll
    for (int i = 0; i < MI; ++i)
#pragma unroll
        for (int j = 0; j < NJ; ++j) acc[i][j] = (f32x4)(0.f);

    STAGE(0, 0);
    int nsteps = K >> 5;
    for (int step = 0; step < nsteps; ++step) {
        int cur = step & 1;
        __syncthreads();   // drains buf[cur] loads; prior reads of buf[cur^1] done
        if (step + 1 < nsteps) STAGE(cur ^ 1, (step + 1) * 32);
        s16x8 af[MI], bf[NJ];
#pragma unroll
        for (int i = 0; i < MI; ++i)
            af[i] = *reinterpret_cast<const s16x8*>(
                As[cur] + (wr * MI * 16 + i * 16 + lr) * 32 + lg * 8);
#pragma unroll
        for (int j = 0; j < NJ; ++j)
            bf[j] = *reinterpret_cast<const s16x8*>(
                Bs[cur] + (wc * NJ * 16 + j * 16 + lr) * 32 + lg * 8);
#pragma unroll
        for (int i = 0; i < MI; ++i)
#pragma unroll
            for (int j = 0; j < NJ; ++j)
                acc[i][j] = __builtin_amdgcn_mfma_f32_16x16x32_bf16(af[i], bf[j], acc[i][j], 0, 0, 0);
    }

    if constexpr (MODE == 2) {
        int s = n0 >> 8;          // 0=q,1=k,2=v (64-wide tiles never cross 256)
        float* dst = (s == 0) ? Oq : (s == 1) ? Ok : Ov;
#pragma unroll
        for (int i = 0; i < MI; ++i)
#pragma unroll
            for (int j = 0; j < NJ; ++j) {
                int cc = (n0 & 255) + wc * NJ * 16 + j * 16 + lr;
                int hh = cc >> 5, dk = cc & 31;
                int grow = m0 + wr * MI * 16 + i * 16 + lg * 4;
                int nn = grow >> 7, rl = grow & 127;
                size_t ho = ((size_t)(nn * HH + hh) * LL + rl) * DK + dk;
#pragma unroll
                for (int q = 0; q < 4; ++q)
                    dst[ho + (size_t)q * DK] = acc[i][j][q];
            }
    } else {
#pragma unroll
        for (int i = 0; i < MI; ++i)
#pragma unroll
            for (int j = 0; j < NJ; ++j) {
                int col = n0 + wc * NJ * 16 + j * 16 + lr;
                float bc = bias[col];
#pragma unroll
                for (int q = 0; q < 4; ++q) {
                    int r = m0 + wr * MI * 16 + i * 16 + lg * 4 + q;
                    float v = fmaxf(acc[i][j][q] + bc, 0.f);
                    Cb[(size_t)r * N + col] = f2b(v);
                }
            }
    }
}

// ---------------------------------------------------------------------------
// Fused [sparse-attention +] GEMM(16x256 full-row tile) + bias + residual +
// LayerNorm. 512 blocks, 4 waves; wave w owns cols w*64..+63.
// BK=64 staging: each buffer holds TWO stride-32 half-tiles (preserves the
// proven conflict geometry; glds dest stays linear). One barrier per 64 K.
// ATT=true: A-tile built in-LDS by the kNN attention prologue (2 thr/task).
// ATT=false: A staged from global bf16 (same two-half scheme, wave 0).
// ---------------------------------------------------------------------------
template <int KK, bool ATT>
__global__ __launch_bounds__(256)
void gg_ln(const unsigned short* __restrict__ A, const unsigned short* __restrict__ Bt,
           const float* __restrict__ qh, const float* __restrict__ kh,
           const float* __restrict__ vh, const float* __restrict__ edges,
           const unsigned long long* __restrict__ idx8,
           const float* __restrict__ m1w, const float* __restrict__ m1b,
           const float* __restrict__ m2w, const float* __restrict__ m2b,
           const float* __restrict__ bias, const float* __restrict__ res,
           const float* __restrict__ g, const float* __restrict__ be,
           float* __restrict__ out, unsigned short* __restrict__ outb) {
    __shared__ unsigned short Afull[ATT ? 16 * 264 : 1];   // attn-built A (bf16)
    __shared__ unsigned short As[ATT ? 1 : 2][2][16 * 32]; // staged A (FF2)
    __shared__ unsigned short Bs[2][2][256 * 32];          // 2 buf x 2 halves x 16KB
    __shared__ float Red[16][4];
    int tid = threadIdx.x;
    int w = tid >> 6, l = tid & 63;
    int lr = l & 15, lg = l >> 4;
    int m0 = blockIdx.x * 16;

    if constexpr (ATT) {
        // ---- sparse kNN attention prologue: 128 tasks x 2 threads ----
        int task = tid >> 1, sub = tid & 1;
        int rl = task & 15, hh = task >> 4;
        int n = m0 >> 7, r = (m0 & 127) + rl;
        int bh = n * HH + hh;
        const float scale = 0.17677669529663687f;   // 1/sqrt(32)
        const float* w0g = m1w + (hh * 2 + 0) * MS;
        const float* w1g = m1w + (hh * 2 + 1) * MS;
        const float* b1g = m1b + hh * MS;
        const float* w2g = m2w + hh * MS;
        float b2v = m2b[hh];

        const float4* qr = reinterpret_cast<const float4*>(
            qh + ((size_t)bh * LL + r) * DK) + sub * 4;
        float4 q[4];
#pragma unroll
        for (int j = 0; j < 4; ++j) q[j] = qr[j];

        unsigned long long pk = idx8[(size_t)n * LL + r];
        const float* kbase = kh + (size_t)bh * LL * DK;
        const float* vbase = vh + (size_t)bh * LL * DK;
        const float* erow = edges + (size_t)(n * LL + r) * LL * 4;

        int col[KNN];
#pragma unroll
        for (int k = 0; k < KNN; ++k) col[k] = (int)((pk >> (k * 8)) & 0xFF);

        float e[KNN];
        float mx = -3.4e38f;
#pragma unroll
        for (int k = 0; k < KNN; ++k) {
            const float4* kr = reinterpret_cast<const float4*>(
                kbase + (size_t)col[k] * DK) + sub * 4;
            float d = 0.f;
#pragma unroll
            for (int j = 0; j < 4; ++j) {
                float4 kv = kr[j];
                d += q[j].x * kv.x + q[j].y * kv.y + q[j].z * kv.z + q[j].w * kv.w;
            }
            d += __shfl_xor(d, 1);      // merge the two 16-dim halves
            d *= scale;
            float cst = erow[col[k] * 4];
            float s = b2v;
#pragma unroll
            for (int m = 0; m < MS; ++m)
                s += fmaxf(d * w0g[m] + cst * w1g[m] + b1g[m], 0.f) * w2g[m];
            e[k] = s;
            mx = fmaxf(mx, s);
        }
        float sum = 0.f;
#pragma unroll
        for (int k = 0; k < KNN; ++k) { e[k] = __expf(e[k] - mx); sum += e[k]; }
        float inv = 1.f / sum;

        float4 att[4];
#pragma unroll
        for (int j = 0; j < 4; ++j) att[j] = make_float4(0.f, 0.f, 0.f, 0.f);
#pragma unroll
        for (int k = 0; k < KNN; ++k) {
            float wgt = e[k] * inv;
            const float4* vr = reinterpret_cast<const float4*>(
                vbase + (size_t)col[k] * DK) + sub * 4;
#pragma unroll
            for (int j = 0; j < 4; ++j) {
                float4 vv = vr[j];
                att[j].x += wgt * vv.x; att[j].y += wgt * vv.y;
                att[j].z += wgt * vv.z; att[j].w += wgt * vv.w;
            }
        }
        unsigned short* arow = Afull + rl * 264 + hh * DK + sub * 16;
#pragma unroll
        for (int j = 0; j < 4; ++j) {
            ushort4 u;
            u.x = f2b(att[j].x); u.y = f2b(att[j].y);
            u.z = f2b(att[j].z); u.w = f2b(att[j].w);
            *reinterpret_cast<ushort4*>(arow + j * 4) = u;
        }
    }

    auto STAGE = [&](int buf, int s2) {     // stages K range [s2*64, s2*64+64)
        int k0 = s2 * 64;
        if constexpr (!ATT) {
            if (w == 0) {
                glds16(A + (size_t)(m0 + (l >> 2)) * KK + k0 + (l & 3) * 8,
                       As[buf][0]);
                glds16(A + (size_t)(m0 + (l >> 2)) * KK + k0 + 32 + (l & 3) * 8,
                       As[buf][1]);
            }
        }
#pragma unroll
        for (int half = 0; half < 2; ++half)
#pragma unroll
            for (int i = 0; i < 4; ++i) {
                int idx = w * 4 + i;    // 16 wave-loads cover 256 B-rows per half
                glds16(Bt + (size_t)(idx * 16 + (l >> 2)) * KK + k0 + half * 32 + (l & 3) * 8,
                       Bs[buf][half] + idx * 512);
            }
    };

    // ---- GEMM: C(16x256) = A(16xKK) @ Bt^T, double-buffered BK=64 ----
    f32x4 acc[4];
#pragma unroll
    for (int j = 0; j < 4; ++j) acc[j] = (f32x4)(0.f);

    STAGE(0, 0);
    constexpr int NS2 = KK >> 6;
    for (int s2 = 0; s2 < NS2; ++s2) {
        int cur = s2 & 1;
        __syncthreads();
        if (s2 + 1 < NS2) STAGE(cur ^ 1, s2 + 1);
#pragma unroll
        for (int half = 0; half < 2; ++half) {
            s16x8 af;
            if constexpr (ATT)
                af = *reinterpret_cast<const s16x8*>(
                    Afull + lr * 264 + (s2 * 2 + half) * 32 + lg * 8);
            else
                af = *reinterpret_cast<const s16x8*>(As[cur][half] + lr * 32 + lg * 8);
#pragma unroll
            for (int j = 0; j < 4; ++j) {
                s16x8 bf = *reinterpret_cast<const s16x8*>(
                    Bs[cur][half] + (w * 64 + j * 16 + lr) * 32 + lg * 8);
                acc[j] = __builtin_amdgcn_mfma_f32_16x16x32_bf16(af, bf, acc[j], 0, 0, 0);
            }
        }
    }

    // ---- epilogue: bias + residual; cross-wave LN ----
    float rsum[4] = {0.f, 0.f, 0.f, 0.f};
#pragma unroll
    for (int j = 0; j < 4; ++j) {
        int col = w * 64 + j * 16 + lr;
        float bc = bias[col];
#pragma unroll
        for (int q = 0; q < 4; ++q) {
            float x = acc[j][q] + bc + res[(size_t)(m0 + lg * 4 + q) * DD + col];
            acc[j][q] = x;
            rsum[q] += x;
        }
    }
#pragma unroll
    for (int q = 0; q < 4; ++q)
#pragma unroll
        for (int o = 1; o < 16; o <<= 1) rsum[q] += __shfl_xor(rsum[q], o);
    __syncthreads();
    if (lr == 0)
#pragma unroll
        for (int q = 0; q < 4; ++q) Red[lg * 4 + q][w] = rsum[q];
    __syncthreads();
    float mean[4];
#pragma unroll
    for (int q = 0; q < 4; ++q) {
        int row = lg * 4 + q;
        mean[q] = (Red[row][0] + Red[row][1] + Red[row][2] + Red[row][3]) * (1.0f / 256.0f);
    }
    float ssum[4] = {0.f, 0.f, 0.f, 0.f};
#pragma unroll
    for (int j = 0; j < 4; ++j)
#pragma unroll
        for (int q = 0; q < 4; ++q) {
            float d = acc[j][q] - mean[q];
            ssum[q] += d * d;
        }
#pragma unroll
    for (int q = 0; q < 4; ++q)
#pragma unroll
        for (int o = 1; o < 16; o <<= 1) ssum[q] += __shfl_xor(ssum[q], o);
    __syncthreads();
    if (lr == 0)
#pragma unroll
        for (int q = 0; q < 4; ++q) Red[lg * 4 + q][w] = ssum[q];
    __syncthreads();
    float rstd[4];
#pragma unroll
    for (int q = 0; q < 4; ++q) {
        int row = lg * 4 + q;
        float var = (Red[row][0] + Red[row][1] + Red[row][2] + Red[row][3]) * (1.0f / 256.0f);
        rstd[q] = 1.0f / sqrtf(var + 1e-5f);
    }
#pragma unroll
    for (int j = 0; j < 4; ++j) {
        int col = w * 64 + j * 16 + lr;
        float gc = g[col], bc2 = be[col];
#pragma unroll
        for (int q = 0; q < 4; ++q) {
            size_t off = (size_t)(m0 + lg * 4 + q) * DD + col;
            float v = (acc[j][q] - mean[q]) * rstd[q] * gc + bc2;
            out[off] = v;
            outb[off] = f2b(v);
        }
    }
}

// ---------------------------------------------------------------------------
extern "C" void kernel_launch(void* const* d_in, const int* in_sizes, int n_in,
                              void* d_out, int out_size, void* d_ws, size_t ws_size,
                              hipStream_t stream) {
    const float* vehicles = (const float*)d_in[0];
    const float* fleet    = (const float*)d_in[1];
    const float* Wproj    = (const float*)d_in[2];
    const float* bproj    = (const float*)d_in[3];
    const float* Wq       = (const float*)d_in[4];
    const float* Wk       = (const float*)d_in[5];
    const float* Wv       = (const float*)d_in[6];
    const float* m1w      = (const float*)d_in[7];
    const float* m1b      = (const float*)d_in[8];
    const float* m2w      = (const float*)d_in[9];
    const float* m2b      = (const float*)d_in[10];
    const float* Wo       = (const float*)d_in[11];
    const float* bo       = (const float*)d_in[12];
    const float* n1_g     = (const float*)d_in[13];
    const float* n1_b     = (const float*)d_in[14];
    const float* ff1_w    = (const float*)d_in[15];
    const float* ff1_b    = (const float*)d_in[16];
    const float* ff2_w    = (const float*)d_in[17];
    const float* ff2_b    = (const float*)d_in[18];
    const float* n2_g     = (const float*)d_in[19];
    const float* n2_b     = (const float*)d_in[20];

    const size_t MROWS = (size_t)NB * LL;           // 8192
    const size_t HSZ   = MROWS * DD;                // 2,097,152

    float* ws = (float*)d_ws;
    float* h   = ws;                                 // HSZ f32
    float* qh  = h + HSZ;                            // HSZ f32
    float* kh  = qh + HSZ;                           // HSZ f32
    float* vh  = kh + HSZ;                           // HSZ f32
    unsigned short* hb    = (unsigned short*)(vh + HSZ);            // HSZ bf16
    unsigned short* ffmid = hb + HSZ;                               // M*FF bf16
    unsigned short* Wt    = ffmid + MROWS * FF;                     // 3*WLS bf16
    unsigned long long* idx8 = (unsigned long long*)(Wt + 3 * WLS); // 8192 u64

    // preprocessing: one dispatch
    uber_pre<<<6400, 256, 0, stream>>>(vehicles, Wproj, bproj, h, hb,
                                       fleet, idx8,
                                       Wq, Wk, Wv, Wo, ff1_w, ff2_w, Wt);

    dim3 gqkv(12, 128);  // QKV: 64x64 tiles, N=768 -> 1536 blocks
    dim3 gff1(8, 128);   // FF1: 64x128 tiles, N=1024 -> 1024 blocks

    for (int i = 0; i < LC; ++i) {
        const unsigned short* wt = Wt + (size_t)i * WLS;

        gg<64, 64, 2, 2, 2><<<gqkv, 256, 0, stream>>>(
            hb, wt, nullptr, nullptr, qh, kh, vh, DD, 768);

        gg_ln<256, true><<<512, 256, 0, stream>>>(
            nullptr, wt + 196608,
            qh, kh, vh, fleet, idx8,
            m1w + (size_t)i * HH * 2 * MS, m1b + (size_t)i * HH * MS,
            m2w + (size_t)i * HH * MS,     m2b + (size_t)i * HH,
            bo + (size_t)i * DD,
            h, n1_g + (size_t)i * DD, n1_b + (size_t)i * DD, h, hb);

        gg<64, 128, 2, 2, 1><<<gff1, 256, 0, stream>>>(
            hb, wt + 262144, ff1_b + (size_t)i * FF, ffmid,
            nullptr, nullptr, nullptr, DD, FF);

        float* dst = (i == LC - 1) ? (float*)d_out : h;
        gg_ln<1024, false><<<512, 256, 0, stream>>>(
            ffmid, wt + 524288,
            nullptr, nullptr, nullptr, nullptr, nullptr,
            nullptr, nullptr, nullptr, nullptr,
            ff2_b + (size_t)i * DD,
            h, n2_g + (size_t)i * DD, n2_b + (size_t)i * DD, dst, hb);
    }
}

// Round 20
// 218.612 us; speedup vs baseline: 1.1121x; 1.0230x over previous
//
#include <hip/hip_runtime.h>
#include <math.h>

// Problem constants
#define NB 64    // N batch
#define LL 128   // L
#define DV 16
#define DD 256   // D
#define HH 8     // heads
#define DK 32    // D/H
#define FF 1024
#define LC 3
#define KNN 6
#define MS 16
#define WLS 786432   // per-layer transposed-weight stride (elems)

typedef __attribute__((ext_vector_type(8))) short s16x8;   // 8 bf16 (4 VGPR)
typedef __attribute__((ext_vector_type(4))) float f32x4;   // MFMA acc

static __device__ inline unsigned short f2b(float x) {
    union { float f; unsigned int u; } v; v.f = x;
    unsigned int r = (v.u + 0x7FFFu + ((v.u >> 16) & 1u)) >> 16;
    return (unsigned short)r;
}

// global -> LDS direct (16B per lane; dest = wave-uniform base + lane*16)
static __device__ __forceinline__ void glds16(const void* g, void* l) {
    __builtin_amdgcn_global_load_lds(
        (const __attribute__((address_space(1))) void*)g,
        (__attribute__((address_space(3))) void*)l, 16, 0, 0);
}

// ---------------------------------------------------------------------------
// Uber preprocessing: [0,2048) proj | [2048,4096) knn | [4096,6400) transpose
// ---------------------------------------------------------------------------
__global__ __launch_bounds__(256)
void uber_pre(const float* __restrict__ veh, const float* __restrict__ Wp,
              const float* __restrict__ bp, float* __restrict__ h,
              unsigned short* __restrict__ hb,
              const float* __restrict__ edges, unsigned long long* __restrict__ idx8,
              const float* __restrict__ Wq, const float* __restrict__ Wk,
              const float* __restrict__ Wv, const float* __restrict__ Wo,
              const float* __restrict__ f1, const float* __restrict__ f2,
              unsigned short* __restrict__ Wt) {
    int bx = blockIdx.x;
    if (bx < 2048) {
        int m = bx * 4 + (threadIdx.x >> 6);
        int l = threadIdx.x & 63;
        int c0 = l * 4;
        const float4* w4 = reinterpret_cast<const float4*>(Wp);
        float4 a = *reinterpret_cast<const float4*>(bp + c0);
        const float* vr = veh + (size_t)m * DV;
#pragma unroll
        for (int t = 0; t < DV; ++t) {
            float vt = vr[t];
            float4 wv = w4[t * 64 + l];
            a.x += vt * wv.x; a.y += vt * wv.y; a.z += vt * wv.z; a.w += vt * wv.w;
        }
        *reinterpret_cast<float4*>(h + (size_t)m * DD + c0) = a;
        ushort4 u; u.x = f2b(a.x); u.y = f2b(a.y); u.z = f2b(a.z); u.w = f2b(a.w);
        *reinterpret_cast<ushort4*>(hb + (size_t)m * DD + c0) = u;
        return;
    }
    if (bx < 4096) {
        int row = (bx - 2048) * 4 + (threadIdx.x >> 6);
        int lane = threadIdx.x & 63;
        const float* dr = edges + (size_t)row * LL * 4;
        float v0 = dr[lane * 4], v1 = dr[(lane + 64) * 4];
        int i0 = lane, i1 = lane + 64;
        unsigned long long packed = 0;
#pragma unroll
        for (int k = 0; k < KNN; ++k) {
            float v; int i;
            if (v1 < v0) { v = v1; i = i1; } else { v = v0; i = i0; }
#pragma unroll
            for (int o = 1; o < 64; o <<= 1) {
                float ov = __shfl_xor(v, o);
                int oi = __shfl_xor(i, o);
                if (ov < v || (ov == v && oi < i)) { v = ov; i = oi; }
            }
            packed |= (unsigned long long)i << (k * 8);
            if (i == i0) v0 = 3.4e38f;
            if (i == i1) v1 = 3.4e38f;
        }
        if (lane == 0) idx8[row] = packed;
        return;
    }
    {
        int t = bx - 4096;            // < 2304
        int ll = t / 768, r = t % 768;
        int w, tile, K, N;
        if (r < 256)      { w = r >> 6; tile = r & 63;  K = DD; N = DD; }
        else if (r < 512) { w = 4; tile = r - 256;      K = DD; N = FF; }
        else              { w = 5; tile = r - 512;      K = FF; N = DD; }
        const float* src = (w == 0) ? Wq : (w == 1) ? Wk : (w == 2) ? Wv :
                           (w == 3) ? Wo : (w == 4) ? f1 : f2;
        src += (size_t)ll * K * N;
        long off = (w == 4) ? 262144L : (w == 5) ? 524288L : (long)w * 65536L;
        unsigned short* dst = Wt + (size_t)ll * WLS + off;
        int ntx = N >> 5;
        int n0 = (tile % ntx) * 32, k0 = (tile / ntx) * 32;
        int tx = threadIdx.x & 31, ty = threadIdx.x >> 5;
        __shared__ float T[32][33];
#pragma unroll
        for (int rr = 0; rr < 4; ++rr)
            T[ty + rr * 8][tx] = src[(size_t)(k0 + ty + rr * 8) * N + n0 + tx];
        __syncthreads();
#pragma unroll
        for (int rr = 0; rr < 4; ++rr)
            dst[(size_t)(n0 + ty + rr * 8) * K + k0 + tx] = f2b(T[tx][ty + rr * 8]);
    }
}

// ---------------------------------------------------------------------------
// Unified MFMA GEMM, double-buffered BK=64 (two stride-32 half-tiles per
// buffer): one barrier per 64 K. MODE 1: bf16+bias+relu (FF1).
// MODE 2: QKV scatter -> f32 head-major (no bias). K must be mult of 64.
// ---------------------------------------------------------------------------
template <int BM, int BN, int WR, int WC, int MODE>
__global__ __launch_bounds__(256)
void gg(const unsigned short* __restrict__ A, const unsigned short* __restrict__ Bt,
        const float* __restrict__ bias, unsigned short* __restrict__ Cb,
        float* __restrict__ Oq, float* __restrict__ Ok, float* __restrict__ Ov,
        int K, int N) {
    constexpr int MI = BM / (WR * 16);
    constexpr int NJ = BN / (WC * 16);
    __shared__ unsigned short As[2][2][BM * 32];
    __shared__ unsigned short Bs[2][2][BN * 32];
    int tid = threadIdx.x;
    int w = tid >> 6, l = tid & 63;
    int lr = l & 15, lg = l >> 4;
    int wr = w % WR, wc = w / WR;
    int m0 = blockIdx.y * BM, n0 = blockIdx.x * BN;
    int row = tid >> 2, seg = tid & 3;

    auto STAGE = [&](int buf, int s2) {
        int k0 = s2 * 64;
#pragma unroll
        for (int half = 0; half < 2; ++half) {
#pragma unroll
            for (int r = 0; r < BM / 64; ++r)
                glds16(A + (size_t)(m0 + r * 64 + row) * K + k0 + half * 32 + seg * 8,
                       As[buf][half] + r * 2048 + w * 512);
#pragma unroll
            for (int r = 0; r < BN / 64; ++r)
                glds16(Bt + (size_t)(n0 + r * 64 + row) * K + k0 + half * 32 + seg * 8,
                       Bs[buf][half] + r * 2048 + w * 512);
        }
    };

    f32x4 acc[MI][NJ];
#pragma unroll
    for (int i = 0; i < MI; ++i)
#pragma unroll
        for (int j = 0; j < NJ; ++j) acc[i][j] = (f32x4)(0.f);

    STAGE(0, 0);
    int ns2 = K >> 6;
    for (int s2 = 0; s2 < ns2; ++s2) {
        int cur = s2 & 1;
        __syncthreads();   // drains buf[cur] loads; prior reads of buf[cur^1] done
        if (s2 + 1 < ns2) STAGE(cur ^ 1, s2 + 1);
#pragma unroll
        for (int half = 0; half < 2; ++half) {
            s16x8 af[MI], bf[NJ];
#pragma unroll
            for (int i = 0; i < MI; ++i)
                af[i] = *reinterpret_cast<const s16x8*>(
                    As[cur][half] + (wr * MI * 16 + i * 16 + lr) * 32 + lg * 8);
#pragma unroll
            for (int j = 0; j < NJ; ++j)
                bf[j] = *reinterpret_cast<const s16x8*>(
                    Bs[cur][half] + (wc * NJ * 16 + j * 16 + lr) * 32 + lg * 8);
#pragma unroll
            for (int i = 0; i < MI; ++i)
#pragma unroll
                for (int j = 0; j < NJ; ++j)
                    acc[i][j] = __builtin_amdgcn_mfma_f32_16x16x32_bf16(af[i], bf[j], acc[i][j], 0, 0, 0);
        }
    }

    if constexpr (MODE == 2) {
        int s = n0 >> 8;          // 0=q,1=k,2=v (64-wide tiles never cross 256)
        float* dst = (s == 0) ? Oq : (s == 1) ? Ok : Ov;
#pragma unroll
        for (int i = 0; i < MI; ++i)
#pragma unroll
            for (int j = 0; j < NJ; ++j) {
                int cc = (n0 & 255) + wc * NJ * 16 + j * 16 + lr;
                int hh = cc >> 5, dk = cc & 31;
                int grow = m0 + wr * MI * 16 + i * 16 + lg * 4;
                int nn = grow >> 7, rl = grow & 127;
                size_t ho = ((size_t)(nn * HH + hh) * LL + rl) * DK + dk;
#pragma unroll
                for (int q = 0; q < 4; ++q)
                    dst[ho + (size_t)q * DK] = acc[i][j][q];
            }
    } else {
#pragma unroll
        for (int i = 0; i < MI; ++i)
#pragma unroll
            for (int j = 0; j < NJ; ++j) {
                int col = n0 + wc * NJ * 16 + j * 16 + lr;
                float bc = bias[col];
#pragma unroll
                for (int q = 0; q < 4; ++q) {
                    int r = m0 + wr * MI * 16 + i * 16 + lg * 4 + q;
                    float v = fmaxf(acc[i][j][q] + bc, 0.f);
                    Cb[(size_t)r * N + col] = f2b(v);
                }
            }
    }
}

// ---------------------------------------------------------------------------
// Fused [sparse-attention +] GEMM(16x256 full-row tile) + bias + residual +
// LayerNorm. 512 blocks, 4 waves; wave w owns cols w*64..+63.
// BK=64 staging (two stride-32 half-tiles); one barrier per 64 K.
// ATT=true: A-tile built in-LDS by the kNN attention prologue (2 thr/task).
// ATT=false: A staged from global bf16 (same two-half scheme, wave 0).
// ---------------------------------------------------------------------------
template <int KK, bool ATT>
__global__ __launch_bounds__(256)
void gg_ln(const unsigned short* __restrict__ A, const unsigned short* __restrict__ Bt,
           const float* __restrict__ qh, const float* __restrict__ kh,
           const float* __restrict__ vh, const float* __restrict__ edges,
           const unsigned long long* __restrict__ idx8,
           const float* __restrict__ m1w, const float* __restrict__ m1b,
           const float* __restrict__ m2w, const float* __restrict__ m2b,
           const float* __restrict__ bias, const float* __restrict__ res,
           const float* __restrict__ g, const float* __restrict__ be,
           float* __restrict__ out, unsigned short* __restrict__ outb) {
    __shared__ unsigned short Afull[ATT ? 16 * 264 : 1];   // attn-built A (bf16)
    __shared__ unsigned short As[ATT ? 1 : 2][2][16 * 32]; // staged A (FF2)
    __shared__ unsigned short Bs[2][2][256 * 32];          // 2 buf x 2 halves x 16KB
    __shared__ float Red[16][4];
    int tid = threadIdx.x;
    int w = tid >> 6, l = tid & 63;
    int lr = l & 15, lg = l >> 4;
    int m0 = blockIdx.x * 16;

    if constexpr (ATT) {
        // ---- sparse kNN attention prologue: 128 tasks x 2 threads ----
        int task = tid >> 1, sub = tid & 1;
        int rl = task & 15, hh = task >> 4;
        int n = m0 >> 7, r = (m0 & 127) + rl;
        int bh = n * HH + hh;
        const float scale = 0.17677669529663687f;   // 1/sqrt(32)
        const float* w0g = m1w + (hh * 2 + 0) * MS;
        const float* w1g = m1w + (hh * 2 + 1) * MS;
        const float* b1g = m1b + hh * MS;
        const float* w2g = m2w + hh * MS;
        float b2v = m2b[hh];

        const float4* qr = reinterpret_cast<const float4*>(
            qh + ((size_t)bh * LL + r) * DK) + sub * 4;
        float4 q[4];
#pragma unroll
        for (int j = 0; j < 4; ++j) q[j] = qr[j];

        unsigned long long pk = idx8[(size_t)n * LL + r];
        const float* kbase = kh + (size_t)bh * LL * DK;
        const float* vbase = vh + (size_t)bh * LL * DK;
        const float* erow = edges + (size_t)(n * LL + r) * LL * 4;

        int col[KNN];
#pragma unroll
        for (int k = 0; k < KNN; ++k) col[k] = (int)((pk >> (k * 8)) & 0xFF);

        float e[KNN];
        float mx = -3.4e38f;
#pragma unroll
        for (int k = 0; k < KNN; ++k) {
            const float4* kr = reinterpret_cast<const float4*>(
                kbase + (size_t)col[k] * DK) + sub * 4;
            float d = 0.f;
#pragma unroll
            for (int j = 0; j < 4; ++j) {
                float4 kv = kr[j];
                d += q[j].x * kv.x + q[j].y * kv.y + q[j].z * kv.z + q[j].w * kv.w;
            }
            d += __shfl_xor(d, 1);      // merge the two 16-dim halves
            d *= scale;
            float cst = erow[col[k] * 4];
            float s = b2v;
#pragma unroll
            for (int m = 0; m < MS; ++m)
                s += fmaxf(d * w0g[m] + cst * w1g[m] + b1g[m], 0.f) * w2g[m];
            e[k] = s;
            mx = fmaxf(mx, s);
        }
        float sum = 0.f;
#pragma unroll
        for (int k = 0; k < KNN; ++k) { e[k] = __expf(e[k] - mx); sum += e[k]; }
        float inv = 1.f / sum;

        float4 att[4];
#pragma unroll
        for (int j = 0; j < 4; ++j) att[j] = make_float4(0.f, 0.f, 0.f, 0.f);
#pragma unroll
        for (int k = 0; k < KNN; ++k) {
            float wgt = e[k] * inv;
            const float4* vr = reinterpret_cast<const float4*>(
                vbase + (size_t)col[k] * DK) + sub * 4;
#pragma unroll
            for (int j = 0; j < 4; ++j) {
                float4 vv = vr[j];
                att[j].x += wgt * vv.x; att[j].y += wgt * vv.y;
                att[j].z += wgt * vv.z; att[j].w += wgt * vv.w;
            }
        }
        unsigned short* arow = Afull + rl * 264 + hh * DK + sub * 16;
#pragma unroll
        for (int j = 0; j < 4; ++j) {
            ushort4 u;
            u.x = f2b(att[j].x); u.y = f2b(att[j].y);
            u.z = f2b(att[j].z); u.w = f2b(att[j].w);
            *reinterpret_cast<ushort4*>(arow + j * 4) = u;
        }
    }

    auto STAGE = [&](int buf, int s2) {     // stages K range [s2*64, s2*64+64)
        int k0 = s2 * 64;
        if constexpr (!ATT) {
            if (w == 0) {
                glds16(A + (size_t)(m0 + (l >> 2)) * KK + k0 + (l & 3) * 8,
                       As[buf][0]);
                glds16(A + (size_t)(m0 + (l >> 2)) * KK + k0 + 32 + (l & 3) * 8,
                       As[buf][1]);
            }
        }
#pragma unroll
        for (int half = 0; half < 2; ++half)
#pragma unroll
            for (int i = 0; i < 4; ++i) {
                int idx = w * 4 + i;    // 16 wave-loads cover 256 B-rows per half
                glds16(Bt + (size_t)(idx * 16 + (l >> 2)) * KK + k0 + half * 32 + (l & 3) * 8,
                       Bs[buf][half] + idx * 512);
            }
    };

    // ---- GEMM: C(16x256) = A(16xKK) @ Bt^T, double-buffered BK=64 ----
    f32x4 acc[4];
#pragma unroll
    for (int j = 0; j < 4; ++j) acc[j] = (f32x4)(0.f);

    STAGE(0, 0);
    constexpr int NS2 = KK >> 6;
    for (int s2 = 0; s2 < NS2; ++s2) {
        int cur = s2 & 1;
        __syncthreads();
        if (s2 + 1 < NS2) STAGE(cur ^ 1, s2 + 1);
#pragma unroll
        for (int half = 0; half < 2; ++half) {
            s16x8 af;
            if constexpr (ATT)
                af = *reinterpret_cast<const s16x8*>(
                    Afull + lr * 264 + (s2 * 2 + half) * 32 + lg * 8);
            else
                af = *reinterpret_cast<const s16x8*>(As[cur][half] + lr * 32 + lg * 8);
#pragma unroll
            for (int j = 0; j < 4; ++j) {
                s16x8 bf = *reinterpret_cast<const s16x8*>(
                    Bs[cur][half] + (w * 64 + j * 16 + lr) * 32 + lg * 8);
                acc[j] = __builtin_amdgcn_mfma_f32_16x16x32_bf16(af, bf, acc[j], 0, 0, 0);
            }
        }
    }

    // ---- epilogue: bias + residual; cross-wave LN ----
    float rsum[4] = {0.f, 0.f, 0.f, 0.f};
#pragma unroll
    for (int j = 0; j < 4; ++j) {
        int col = w * 64 + j * 16 + lr;
        float bc = bias[col];
#pragma unroll
        for (int q = 0; q < 4; ++q) {
            float x = acc[j][q] + bc + res[(size_t)(m0 + lg * 4 + q) * DD + col];
            acc[j][q] = x;
            rsum[q] += x;
        }
    }
#pragma unroll
    for (int q = 0; q < 4; ++q)
#pragma unroll
        for (int o = 1; o < 16; o <<= 1) rsum[q] += __shfl_xor(rsum[q], o);
    __syncthreads();
    if (lr == 0)
#pragma unroll
        for (int q = 0; q < 4; ++q) Red[lg * 4 + q][w] = rsum[q];
    __syncthreads();
    float mean[4];
#pragma unroll
    for (int q = 0; q < 4; ++q) {
        int row = lg * 4 + q;
        mean[q] = (Red[row][0] + Red[row][1] + Red[row][2] + Red[row][3]) * (1.0f / 256.0f);
    }
    float ssum[4] = {0.f, 0.f, 0.f, 0.f};
#pragma unroll
    for (int j = 0; j < 4; ++j)
#pragma unroll
        for (int q = 0; q < 4; ++q) {
            float d = acc[j][q] - mean[q];
            ssum[q] += d * d;
        }
#pragma unroll
    for (int q = 0; q < 4; ++q)
#pragma unroll
        for (int o = 1; o < 16; o <<= 1) ssum[q] += __shfl_xor(ssum[q], o);
    __syncthreads();
    if (lr == 0)
#pragma unroll
        for (int q = 0; q < 4; ++q) Red[lg * 4 + q][w] = ssum[q];
    __syncthreads();
    float rstd[4];
#pragma unroll
    for (int q = 0; q < 4; ++q) {
        int row = lg * 4 + q;
        float var = (Red[row][0] + Red[row][1] + Red[row][2] + Red[row][3]) * (1.0f / 256.0f);
        rstd[q] = 1.0f / sqrtf(var + 1e-5f);
    }
#pragma unroll
    for (int j = 0; j < 4; ++j) {
        int col = w * 64 + j * 16 + lr;
        float gc = g[col], bc2 = be[col];
#pragma unroll
        for (int q = 0; q < 4; ++q) {
            size_t off = (size_t)(m0 + lg * 4 + q) * DD + col;
            float v = (acc[j][q] - mean[q]) * rstd[q] * gc + bc2;
            out[off] = v;
            outb[off] = f2b(v);
        }
    }
}

// ---------------------------------------------------------------------------
extern "C" void kernel_launch(void* const* d_in, const int* in_sizes, int n_in,
                              void* d_out, int out_size, void* d_ws, size_t ws_size,
                              hipStream_t stream) {
    const float* vehicles = (const float*)d_in[0];
    const float* fleet    = (const float*)d_in[1];
    const float* Wproj    = (const float*)d_in[2];
    const float* bproj    = (const float*)d_in[3];
    const float* Wq       = (const float*)d_in[4];
    const float* Wk       = (const float*)d_in[5];
    const float* Wv       = (const float*)d_in[6];
    const float* m1w      = (const float*)d_in[7];
    const float* m1b      = (const float*)d_in[8];
    const float* m2w      = (const float*)d_in[9];
    const float* m2b      = (const float*)d_in[10];
    const float* Wo       = (const float*)d_in[11];
    const float* bo       = (const float*)d_in[12];
    const float* n1_g     = (const float*)d_in[13];
    const float* n1_b     = (const float*)d_in[14];
    const float* ff1_w    = (const float*)d_in[15];
    const float* ff1_b    = (const float*)d_in[16];
    const float* ff2_w    = (const float*)d_in[17];
    const float* ff2_b    = (const float*)d_in[18];
    const float* n2_g     = (const float*)d_in[19];
    const float* n2_b     = (const float*)d_in[20];

    const size_t MROWS = (size_t)NB * LL;           // 8192
    const size_t HSZ   = MROWS * DD;                // 2,097,152

    float* ws = (float*)d_ws;
    float* h   = ws;                                 // HSZ f32
    float* qh  = h + HSZ;                            // HSZ f32
    float* kh  = qh + HSZ;                           // HSZ f32
    float* vh  = kh + HSZ;                           // HSZ f32
    unsigned short* hb    = (unsigned short*)(vh + HSZ);            // HSZ bf16
    unsigned short* ffmid = hb + HSZ;                               // M*FF bf16
    unsigned short* Wt    = ffmid + MROWS * FF;                     // 3*WLS bf16
    unsigned long long* idx8 = (unsigned long long*)(Wt + 3 * WLS); // 8192 u64

    // preprocessing: one dispatch
    uber_pre<<<6400, 256, 0, stream>>>(vehicles, Wproj, bproj, h, hb,
                                       fleet, idx8,
                                       Wq, Wk, Wv, Wo, ff1_w, ff2_w, Wt);

    dim3 gqkv(12, 128);  // QKV: 64x64 tiles, N=768 -> 1536 blocks
    dim3 gff1(16, 128);  // FF1: 64x64 tiles, N=1024 -> 2048 blocks

    for (int i = 0; i < LC; ++i) {
        const unsigned short* wt = Wt + (size_t)i * WLS;

        gg<64, 64, 2, 2, 2><<<gqkv, 256, 0, stream>>>(
            hb, wt, nullptr, nullptr, qh, kh, vh, DD, 768);

        gg_ln<256, true><<<512, 256, 0, stream>>>(
            nullptr, wt + 196608,
            qh, kh, vh, fleet, idx8,
            m1w + (size_t)i * HH * 2 * MS, m1b + (size_t)i * HH * MS,
            m2w + (size_t)i * HH * MS,     m2b + (size_t)i * HH,
            bo + (size_t)i * DD,
            h, n1_g + (size_t)i * DD, n1_b + (size_t)i * DD, h, hb);

        gg<64, 64, 2, 2, 1><<<gff1, 256, 0, stream>>>(
            hb, wt + 262144, ff1_b + (size_t)i * FF, ffmid,
            nullptr, nullptr, nullptr, DD, FF);

        float* dst = (i == LC - 1) ? (float*)d_out : h;
        gg_ln<1024, false><<<512, 256, 0, stream>>>(
            ffmid, wt + 524288,
            nullptr, nullptr, nullptr, nullptr, nullptr,
            nullptr, nullptr, nullptr, nullptr,
            ff2_b + (size_t)i * DD,
            h, n2_g + (size_t)i * DD, n2_b + (size_t)i * DD, dst, hb);
    }
}